// Round 10
// baseline (512.483 us; speedup 1.0000x reference)
//
#include <hip/hip_runtime.h>
#include <hip/hip_bf16.h>

#define NN   20000
#define E1N  100000
#define E2N  100000
#define NEFF 220000                     /* effective edges (skip row>=n half of E3d) */
#define TILE 64
#define NBLK ((NEFF + TILE - 1) / TILE) /* 3438 */
#define NPAD (NBLK * TILE)              /* 220032 */
#define RBF_STEP   0.09523809523809523f /* 6/63 */
#define RBF_INV2W2 56.88888888888889f   /* 1/(2*(6/64)^2) */

typedef short  bf16x8 __attribute__((ext_vector_type(8)));
typedef float  f32x4  __attribute__((ext_vector_type(4)));

__device__ __forceinline__ float4 ld4(const float* p) {
    return *reinterpret_cast<const float4*>(p);
}
__device__ __forceinline__ ushort f2bf(float x) {
    __hip_bfloat16 h = __float2bfloat16(x);
    return *reinterpret_cast<ushort*>(&h);
}
__device__ __forceinline__ float bf2f(ushort u) {
    return __uint_as_float(((unsigned)u) << 16);
}
__device__ __forceinline__ float env_of(float d) {
    float x = fminf(fmaxf(d * (1.0f / 6.0f), 0.0f), 1.0f);
    return 0.5f * (__cosf(3.14159265358979f * x) + 1.0f);
}
__device__ __forceinline__ float clip100(float x) {
    return fminf(fmaxf(x, -100.f), 100.f);
}

__device__ __forceinline__ int edge_row(int eid, const int* __restrict__ E2d_idx,
                                        const int* __restrict__ Edist_idx) {
    if (eid < E1N) return E2d_idx[eid];
    if (eid < E1N + NN) return eid - E1N;
    return Edist_idx[eid - E1N - NN];
}

// ---------------- sort pipeline ----------------
__global__ __launch_bounds__(256) void hist_kernel(
    const int* __restrict__ E2d_idx, const int* __restrict__ Edist_idx,
    int* __restrict__ hist) {
    int g = blockIdx.x * 256 + threadIdx.x;
    if (g < NEFF) atomicAdd(&hist[edge_row(g, E2d_idx, Edist_idx)], 1);
}

__global__ __launch_bounds__(1024) void scan_kernel(
    const int* __restrict__ hist, int* __restrict__ start, int* __restrict__ cursor) {
    __shared__ int buf[1024];
    __shared__ int carry;
    const int t = threadIdx.x;
    if (t == 0) carry = 0;
    __syncthreads();
    for (int chunk = 0; chunk < 20; ++chunk) {
        int idx = chunk * 1024 + t;
        int v = (idx < NN) ? hist[idx] : 0;
        buf[t] = v;
        __syncthreads();
        for (int off = 1; off < 1024; off <<= 1) {
            int x = (t >= off) ? buf[t - off] : 0;
            __syncthreads();
            buf[t] += x;
            __syncthreads();
        }
        int excl  = buf[t] - v;
        int cbase = carry;
        int tot   = buf[1023];
        if (idx <= NN) {
            start[idx] = cbase + excl;
            if (idx < NN) cursor[idx] = cbase + excl;
        }
        __syncthreads();
        if (t == 0) carry = cbase + tot;
        __syncthreads();
    }
}

__global__ __launch_bounds__(256) void scatter_kernel(
    const int* __restrict__ E2d_idx, const int* __restrict__ Edist_idx,
    int* __restrict__ cursor, int* __restrict__ order) {
    int g = blockIdx.x * 256 + threadIdx.x;
    if (g < NEFF) {
        int r = edge_row(g, E2d_idx, Edist_idx);
        int pos = atomicAdd(&cursor[r], 1);
        order[pos] = g;
    }
}

// ---------------- meta: per-sorted-edge precompute ----------------
__global__ __launch_bounds__(256) void meta_kernel(
    const int* __restrict__ order, const int* __restrict__ E2d_idx,
    const int* __restrict__ Edist_idx, const float* __restrict__ Edist_val,
    const float* __restrict__ Z, const float* __restrict__ Z3d,
    int4* __restrict__ metaI, float4* __restrict__ metaF,
    float4* __restrict__ metaU) {
    int g = blockIdx.x * 256 + threadIdx.x;
    if (g >= NPAD) return;
    int eid = (g < NEFF) ? order[g] : -1;
    int row, col, ty, e2 = 0; float dval = 0.f;
    if (eid < 0)             { ty = 1; row = -1; col = 0; }
    else if (eid < E1N)      { ty = 0; row = E2d_idx[eid]; col = E2d_idx[E1N + eid]; e2 = eid; }
    else if (eid < E1N + NN) { ty = 1; int jj = eid - E1N; row = jj; col = jj + NN; }
    else { ty = 2; int g2 = eid - E1N - NN;
           row = Edist_idx[g2]; col = Edist_idx[E2N + g2]; dval = Edist_val[g2]; }
    int rs = (row < 0) ? 0 : row;
    float prx = Z[rs * 3], pry = Z[rs * 3 + 1], prz = Z[rs * 3 + 2];
    float pcx, pcy, pcz;
    if (col < NN) { pcx = Z[col * 3]; pcy = Z[col * 3 + 1]; pcz = Z[col * 3 + 2]; }
    else { int c = col - NN; pcx = Z3d[c * 3]; pcy = Z3d[c * 3 + 1]; pcz = Z3d[c * 3 + 2]; }
    float dx = prx - pcx, dy = pry - pcy, dz = prz - pcz;
    float dist = sqrtf(dx * dx + dy * dy + dz * dz + 1e-8f);
    float inv = 1.0f / dist;
    int vcol = (col < NN) ? col : -1;
    metaI[g] = make_int4(col, row, ty, e2);
    metaF[g] = make_float4(dist, dval, env_of(dist), env_of(dval));
    metaU[g] = (row >= 0)
        ? make_float4(dx * inv, dy * inv, dz * inv, __int_as_float(vcol))
        : make_float4(0.f, 0.f, 0.f, __int_as_float(-1));
}

// ---------------- prep: folded/bf16 weights (+ Wib for nodes MFMA) ----------------
__global__ __launch_bounds__(256) void prep_kernel(
    const float* __restrict__ W_phi1, const float* __restrict__ b_phi1,
    const float* __restrict__ W_e2d, const float* __restrict__ W_rbf,
    const float* __restrict__ W_phi2, const float* __restrict__ W_msg,
    const float* __restrict__ et, const float* __restrict__ W_i,
    ushort* __restrict__ W1c, ushort* __restrict__ W2b,
    ushort* __restrict__ Wmb, float* __restrict__ b_type,
    ushort* __restrict__ Wib) {
    int g = blockIdx.x * 256 + threadIdx.x;
    if (g < 32768) {
        int n = g >> 8, k = g & 255;
        float v;
        if (k < 128) v = W_phi1[n * 288 + k];
        else {
            int kk = k - 128;
            const float* Wsel = (kk < 64) ? W_e2d : W_rbf;  // both (128,64)
            int j = kk & 63;
            float s = 0.f;
            for (int a = 0; a < 128; ++a) s += W_phi1[n * 288 + 128 + a] * Wsel[a * 64 + j];
            v = s;
        }
        W1c[n * 256 + k] = f2bf(v);
    } else if (g < 81920) {
        int q = g - 32768; W2b[q] = f2bf(W_phi2[q]);
    } else if (g < 106496) {
        int q = g - 81920; Wmb[q] = f2bf(W_msg[q]);
    } else if (g < 106880) {
        int q = g - 106496; int ty = q >> 7, n = q & 127;
        float s = b_phi1[n];
        for (int a = 0; a < 32; ++a) s += W_phi1[n * 288 + 256 + a] * et[ty * 32 + a];
        b_type[q] = s;
    } else if (g < 139648) {
        int q = g - 106880; Wib[q] = f2bf(W_i[q]);
    }
}

// ---------------- featT: transpose E2d_feat (64,E1N) -> bf16 (E1N,64) ----------------
__global__ __launch_bounds__(256) void featT_kernel(
    const float* __restrict__ feat, ushort* __restrict__ featTb) {
    __shared__ float tile[64][65];
    const int t = threadIdx.x;
    const int cbase = blockIdx.x * 64;
    for (int i = t; i < 64 * 64; i += 256) {
        int k = i >> 6, e = i & 63;
        tile[k][e] = (cbase + e < E1N) ? feat[(size_t)k * E1N + cbase + e] : 0.f;
    }
    __syncthreads();
    for (int i = t; i < 64 * 64; i += 256) {
        int e = i >> 6, k = i & 63;
        if (cbase + e < E1N) featTb[(size_t)(cbase + e) * 64 + k] = f2bf(tile[k][e]);
    }
}

// ---------------- nodes (MFMA): nodesb = bf16(concat([H||H2d, H||virt]) @ W_i.T) ----------------
__global__ __launch_bounds__(256, 2) void nodes_mfma_kernel(
    const float* __restrict__ H, const float* __restrict__ H2d,
    const float* __restrict__ virt, const ushort* __restrict__ Wib,
    ushort* __restrict__ nodesb) {
    __shared__ ushort A[64][264];
    __shared__ ushort WB[128][132];

    const int t = threadIdx.x;
    const int gbase = blockIdx.x * 64;

    for (int i = t; i < 64 * 64; i += 256) {   // stage A: f32 -> bf16
        int e = i >> 6, q = i & 63;
        int row = gbase + e;
        float4 v;
        if (q < 32)          v = ld4(H + (size_t)((row < NN) ? row : row - NN) * 128 + q * 4);
        else if (row < NN)   v = ld4(H2d + (size_t)row * 128 + (q - 32) * 4);
        else                 v = ld4(virt + (q - 32) * 4);
        ushort tmp[4] = {f2bf(v.x), f2bf(v.y), f2bf(v.z), f2bf(v.w)};
        *reinterpret_cast<uint2*>(&A[e][q * 4]) = *reinterpret_cast<const uint2*>(tmp);
    }
    for (int i = t; i < 128 * 16; i += 256) {  // WB <- Wib[:, 0:128]
        int n = i >> 4, q = i & 15;
        *reinterpret_cast<uint4*>(&WB[n][q * 8]) =
            *reinterpret_cast<const uint4*>(Wib + (size_t)n * 256 + q * 8);
    }
    __syncthreads();

    const int w  = t >> 6, lane = t & 63;
    const int mh = w >> 1, nh = w & 1;
    const int lr = lane >> 4, lc = lane & 15;
    const int ar0 = mh * 32 + lc;

    f32x4 acc[2][4];
#pragma unroll
    for (int mt = 0; mt < 2; ++mt)
#pragma unroll
        for (int nt = 0; nt < 4; ++nt) acc[mt][nt] = (f32x4){0.f, 0.f, 0.f, 0.f};
#pragma unroll
    for (int ks = 0; ks < 4; ++ks) {
        bf16x8 a0 = *reinterpret_cast<const bf16x8*>(&A[ar0][ks * 32 + lr * 8]);
        bf16x8 a1 = *reinterpret_cast<const bf16x8*>(&A[ar0 + 16][ks * 32 + lr * 8]);
#pragma unroll
        for (int nt = 0; nt < 4; ++nt) {
            int n = nh * 64 + nt * 16 + lc;
            bf16x8 b = *reinterpret_cast<const bf16x8*>(&WB[n][ks * 32 + lr * 8]);
            acc[0][nt] = __builtin_amdgcn_mfma_f32_16x16x32_bf16(a0, b, acc[0][nt], 0, 0, 0);
            acc[1][nt] = __builtin_amdgcn_mfma_f32_16x16x32_bf16(a1, b, acc[1][nt], 0, 0, 0);
        }
    }
    __syncthreads();
    for (int i = t; i < 128 * 16; i += 256) {  // WB <- Wib[:, 128:256]
        int n = i >> 4, q = i & 15;
        *reinterpret_cast<uint4*>(&WB[n][q * 8]) =
            *reinterpret_cast<const uint4*>(Wib + (size_t)n * 256 + 128 + q * 8);
    }
    __syncthreads();
#pragma unroll
    for (int ks = 4; ks < 8; ++ks) {
        bf16x8 a0 = *reinterpret_cast<const bf16x8*>(&A[ar0][ks * 32 + lr * 8]);
        bf16x8 a1 = *reinterpret_cast<const bf16x8*>(&A[ar0 + 16][ks * 32 + lr * 8]);
#pragma unroll
        for (int nt = 0; nt < 4; ++nt) {
            int n = nh * 64 + nt * 16 + lc;
            bf16x8 b = *reinterpret_cast<const bf16x8*>(&WB[n][(ks - 4) * 32 + lr * 8]);
            acc[0][nt] = __builtin_amdgcn_mfma_f32_16x16x32_bf16(a0, b, acc[0][nt], 0, 0, 0);
            acc[1][nt] = __builtin_amdgcn_mfma_f32_16x16x32_bf16(a1, b, acc[1][nt], 0, 0, 0);
        }
    }
#pragma unroll
    for (int mt = 0; mt < 2; ++mt)
#pragma unroll
        for (int nt = 0; nt < 4; ++nt)
#pragma unroll
            for (int r = 0; r < 4; ++r) {
                int e  = mh * 32 + mt * 16 + lr * 4 + r;
                int ch = nh * 64 + nt * 16 + lc;
                nodesb[(size_t)(gbase + e) * 128 + ch] = f2bf(acc[mt][nt][r]);
            }
}

// ---------------- fused MFMA edge pipeline + in-kernel segmented reduction ----------------
// MODE 0: atomic scatter (fallback). MODE 1: sorted tile, local segment reduce,
// interior rows plain-stored (clipped), boundary rows atomicAdd.
template <int MODE>
__global__ __launch_bounds__(256, 2) void edge_kernel(
    const ushort* __restrict__ nodesb, const float* __restrict__ V,
    const float* __restrict__ Z, const float* __restrict__ Z3d,
    const int* __restrict__ E2d_idx, const float* __restrict__ E2d_feat,
    const ushort* __restrict__ featTb,
    const int* __restrict__ Edist_idx, const float* __restrict__ Edist_val,
    const ushort* __restrict__ W1c, const ushort* __restrict__ W2b,
    const ushort* __restrict__ Wmb, const float* __restrict__ b_type,
    const float* __restrict__ b_phi2, const float* __restrict__ b_msg,
    const int4* __restrict__ metaI, const float4* __restrict__ metaF,
    const float4* __restrict__ metaU, const int* __restrict__ start,
    float* __restrict__ Hout, float* __restrict__ Vout) {

    // flat LDS: A1 phase stride 264 (16896); then hid stride 136 (8704);
    // then plane0 = [0,8448) and plane1 = [8448,16896) stride-132 bf16 tiles.
    __shared__ ushort A1f[TILE * 264 + 256];
    __shared__ ushort WB[128][132];
    __shared__ float  s_bt[3][128];
    __shared__ int    s_row[TILE], s_col[TILE], s_ty[TILE], s_e2[TILE], s_vcol[TILE];
    __shared__ float  s_dist[TILE], s_dval[TILE], s_env[TILE], s_env2[TILE];
    __shared__ float  s_unit[TILE][3];

    ushort* hidp   = A1f;          // stride 136
    ushort* plane0 = A1f;          // stride 132
    ushort* plane1 = A1f + 8448;   // stride 132

    const int t = threadIdx.x;
    const int gbase = blockIdx.x * TILE;
    const int pg = gbase;          // global sorted position of tile start

    // ---- edge meta ----
    if (MODE == 1) {
        if (t < TILE) {
            int4 mi = metaI[gbase + t];
            s_col[t] = mi.x; s_row[t] = mi.y; s_ty[t] = mi.z; s_e2[t] = mi.w;
            float4 u = metaU[gbase + t];
            s_unit[t][0] = u.x; s_unit[t][1] = u.y; s_unit[t][2] = u.z;
            s_vcol[t] = __float_as_int(u.w);
        } else if (t < 2 * TILE) {
            int e = t - TILE;
            float4 mf = metaF[gbase + e];
            s_dist[e] = mf.x; s_dval[e] = mf.y; s_env[e] = mf.z; s_env2[e] = mf.w;
        }
    } else {
        if (t < TILE) {
            int gpos = gbase + t;
            int eid = (gpos < NEFF) ? gpos : -1;
            int row, col, ty, e2 = 0; float dval = 0.f;
            if (eid < 0)             { ty = 1; row = -1; col = 0; }
            else if (eid < E1N)      { ty = 0; row = E2d_idx[eid]; col = E2d_idx[E1N + eid]; e2 = eid; }
            else if (eid < E1N + NN) { ty = 1; int jj = eid - E1N; row = jj; col = jj + NN; }
            else { ty = 2; int g2 = eid - E1N - NN;
                   row = Edist_idx[g2]; col = Edist_idx[E2N + g2]; dval = Edist_val[g2]; }
            int rs = (row < 0) ? 0 : row;
            float prx = Z[rs * 3], pry = Z[rs * 3 + 1], prz = Z[rs * 3 + 2];
            float pcx, pcy, pcz;
            if (col < NN) { pcx = Z[col * 3]; pcy = Z[col * 3 + 1]; pcz = Z[col * 3 + 2]; }
            else { int c = col - NN; pcx = Z3d[c * 3]; pcy = Z3d[c * 3 + 1]; pcz = Z3d[c * 3 + 2]; }
            float dx = prx - pcx, dy = pry - pcy, dz = prz - pcz;
            float dist = sqrtf(dx * dx + dy * dy + dz * dz + 1e-8f);
            float inv = 1.0f / dist;
            s_row[t] = row; s_col[t] = col; s_ty[t] = ty; s_e2[t] = e2;
            s_vcol[t] = (col < NN) ? col : -1;
            s_unit[t][0] = dx * inv; s_unit[t][1] = dy * inv; s_unit[t][2] = dz * inv;
            s_dist[t] = dist; s_dval[t] = dval;
            s_env[t] = env_of(dist); s_env2[t] = env_of(dval);
        }
    }
    for (int i = t; i < 384; i += 256) ((float*)s_bt)[i] = b_type[i];
    __syncthreads();

    // ---- phase A: stage A1 = [nodes_bf16[col] | attr] and WB <- W1c K-half 0 ----
    for (int i = t; i < TILE * 16; i += 256) {
        int e = i >> 4, q = i & 15;
        *reinterpret_cast<uint4*>(&A1f[e * 264 + q * 8]) =
            *reinterpret_cast<const uint4*>(nodesb + (size_t)s_col[e] * 128 + q * 8);
    }
    if (MODE == 1) {
        for (int i = t; i < TILE * 128; i += 256) {
            int e = i >> 7, k = i & 127;
            int ty = s_ty[e];
            ushort v = 0;
            if (ty == 0) { if (k < 64) v = featTb[(size_t)s_e2[e] * 64 + k]; }
            else if (ty == 2) {
                if (k >= 64) {
                    float dd = s_dval[e] - (float)(k - 64) * RBF_STEP;
                    v = f2bf(__expf(-dd * dd * RBF_INV2W2) * s_env2[e]);
                }
            }
            A1f[e * 264 + 128 + k] = v;
        }
    } else {
        for (int i = t; i < TILE * 128; i += 256) {
            int k = i >> 6, e = i & 63;
            int ty = s_ty[e];
            float v = 0.f;
            if (ty == 0) { if (k < 64) v = E2d_feat[(size_t)k * E1N + s_e2[e]]; }
            else if (ty == 2) {
                if (k >= 64) {
                    float dd = s_dval[e] - (float)(k - 64) * RBF_STEP;
                    v = __expf(-dd * dd * RBF_INV2W2) * s_env2[e];
                }
            }
            A1f[e * 264 + 128 + k] = f2bf(v);
        }
    }
    for (int i = t; i < 128 * 16; i += 256) {      // WB <- W1c[:, 0:128]
        int n = i >> 4, q = i & 15;
        *reinterpret_cast<uint4*>(&WB[n][q * 8]) =
            *reinterpret_cast<const uint4*>(W1c + (size_t)n * 256 + q * 8);
    }
    __syncthreads();

    const int w  = t >> 6, lane = t & 63;
    const int mh = w >> 1, nh = w & 1;
    const int lr = lane >> 4, lc = lane & 15;
    const int ar0 = mh * 32 + lc;

    // ---- wd A-fragments in-register: rbf(dist) ----
    bf16x8 ra0[2], ra1[2];
    {
        float dA = s_dist[ar0],      eA = s_env[ar0];
        float dB = s_dist[ar0 + 16], eB = s_env[ar0 + 16];
#pragma unroll
        for (int ks = 0; ks < 2; ++ks)
#pragma unroll
            for (int j = 0; j < 8; ++j) {
                float c  = (float)(ks * 32 + lr * 8 + j) * RBF_STEP;
                float tA = dA - c, tB = dB - c;
                ra0[ks][j] = (short)f2bf(__expf(-tA * tA * RBF_INV2W2) * eA);
                ra1[ks][j] = (short)f2bf(__expf(-tB * tB * RBF_INV2W2) * eB);
            }
    }

    // ---- phi1 ----
    f32x4 acc[2][4];
#pragma unroll
    for (int mt = 0; mt < 2; ++mt)
#pragma unroll
        for (int nt = 0; nt < 4; ++nt) acc[mt][nt] = (f32x4){0.f, 0.f, 0.f, 0.f};
#pragma unroll
    for (int ks = 0; ks < 4; ++ks) {
        bf16x8 a0 = *reinterpret_cast<const bf16x8*>(&A1f[ar0 * 264 + ks * 32 + lr * 8]);
        bf16x8 a1 = *reinterpret_cast<const bf16x8*>(&A1f[(ar0 + 16) * 264 + ks * 32 + lr * 8]);
#pragma unroll
        for (int nt = 0; nt < 4; ++nt) {
            int n = nh * 64 + nt * 16 + lc;
            bf16x8 b = *reinterpret_cast<const bf16x8*>(&WB[n][ks * 32 + lr * 8]);
            acc[0][nt] = __builtin_amdgcn_mfma_f32_16x16x32_bf16(a0, b, acc[0][nt], 0, 0, 0);
            acc[1][nt] = __builtin_amdgcn_mfma_f32_16x16x32_bf16(a1, b, acc[1][nt], 0, 0, 0);
        }
    }
    __syncthreads();
    for (int i = t; i < 128 * 16; i += 256) {      // WB <- W1c[:, 128:256]
        int n = i >> 4, q = i & 15;
        *reinterpret_cast<uint4*>(&WB[n][q * 8]) =
            *reinterpret_cast<const uint4*>(W1c + (size_t)n * 256 + 128 + q * 8);
    }
    __syncthreads();
#pragma unroll
    for (int ks = 4; ks < 8; ++ks) {
        bf16x8 a0 = *reinterpret_cast<const bf16x8*>(&A1f[ar0 * 264 + ks * 32 + lr * 8]);
        bf16x8 a1 = *reinterpret_cast<const bf16x8*>(&A1f[(ar0 + 16) * 264 + ks * 32 + lr * 8]);
#pragma unroll
        for (int nt = 0; nt < 4; ++nt) {
            int n = nh * 64 + nt * 16 + lc;
            bf16x8 b = *reinterpret_cast<const bf16x8*>(&WB[n][(ks - 4) * 32 + lr * 8]);
            acc[0][nt] = __builtin_amdgcn_mfma_f32_16x16x32_bf16(a0, b, acc[0][nt], 0, 0, 0);
            acc[1][nt] = __builtin_amdgcn_mfma_f32_16x16x32_bf16(a1, b, acc[1][nt], 0, 0, 0);
        }
    }
    __syncthreads();

    // ---- silu -> hid; stage WB <- W2b c=0 ----
#pragma unroll
    for (int mt = 0; mt < 2; ++mt)
#pragma unroll
        for (int nt = 0; nt < 4; ++nt)
#pragma unroll
            for (int r = 0; r < 4; ++r) {
                int e  = mh * 32 + mt * 16 + lr * 4 + r;
                int ch = nh * 64 + nt * 16 + lc;
                float x = acc[mt][nt][r] + s_bt[s_ty[e]][ch];
                hidp[e * 136 + ch] = f2bf(x / (1.0f + __expf(-x)));
            }
    for (int i = t; i < 128 * 16; i += 256) {
        int n = i >> 4, q = i & 15;
        *reinterpret_cast<uint4*>(&WB[n][q * 8]) =
            *reinterpret_cast<const uint4*>(W2b + (size_t)n * 128 + q * 8);
    }
    __syncthreads();

    // ---- hoist hid A-fragments ----
    bf16x8 ha0[4], ha1[4];
#pragma unroll
    for (int ks = 0; ks < 4; ++ks) {
        ha0[ks] = *reinterpret_cast<const bf16x8*>(&hidp[ar0 * 136 + ks * 32 + lr * 8]);
        ha1[ks] = *reinterpret_cast<const bf16x8*>(&hidp[(ar0 + 16) * 136 + ks * 32 + lr * 8]);
    }

    f32x4 vgr[2][4];
#pragma unroll
    for (int c = 0; c < 3; ++c) {
        f32x4 p[2][4], g[2][4];
#pragma unroll
        for (int mt = 0; mt < 2; ++mt)
#pragma unroll
            for (int nt = 0; nt < 4; ++nt) {
                p[mt][nt] = (f32x4){0.f, 0.f, 0.f, 0.f};
                g[mt][nt] = (f32x4){0.f, 0.f, 0.f, 0.f};
            }
#pragma unroll
        for (int ks = 0; ks < 4; ++ks) {
#pragma unroll
            for (int nt = 0; nt < 4; ++nt) {
                int n = nh * 64 + nt * 16 + lc;
                bf16x8 b = *reinterpret_cast<const bf16x8*>(&WB[n][ks * 32 + lr * 8]);
                p[0][nt] = __builtin_amdgcn_mfma_f32_16x16x32_bf16(ha0[ks], b, p[0][nt], 0, 0, 0);
                p[1][nt] = __builtin_amdgcn_mfma_f32_16x16x32_bf16(ha1[ks], b, p[1][nt], 0, 0, 0);
            }
        }
#pragma unroll
        for (int ks = 0; ks < 2; ++ks) {
#pragma unroll
            for (int nt = 0; nt < 4; ++nt) {
                int n = c * 128 + nh * 64 + nt * 16 + lc;
                bf16x8 b = *reinterpret_cast<const bf16x8*>(Wmb + (size_t)n * 64 + ks * 32 + lr * 8);
                g[0][nt] = __builtin_amdgcn_mfma_f32_16x16x32_bf16(ra0[ks], b, g[0][nt], 0, 0, 0);
                g[1][nt] = __builtin_amdgcn_mfma_f32_16x16x32_bf16(ra1[ks], b, g[1][nt], 0, 0, 0);
            }
        }
        __syncthreads();               // WB reads for this c done; planes free

        if (MODE == 1) {
            ushort* dst = (c == 1) ? plane1 : plane0;
#pragma unroll
            for (int mt = 0; mt < 2; ++mt)
#pragma unroll
                for (int nt = 0; nt < 4; ++nt) {
                    int d  = nh * 64 + nt * 16 + lc;
                    float b2 = b_phi2[c * 128 + d];
                    float bm = b_msg[c * 128 + d];
#pragma unroll
                    for (int r = 0; r < 4; ++r) {
                        int e = mh * 32 + mt * 16 + lr * 4 + r;
                        dst[e * 132 + d] = f2bf((p[mt][nt][r] + b2) * (g[mt][nt][r] + bm));
                    }
                }
            if (c == 1) {              // stage WB <- W2b c=2 in same phase
                for (int i = t; i < 128 * 16; i += 256) {
                    int n = i >> 4, q = i & 15;
                    *reinterpret_cast<uint4*>(&WB[n][q * 8]) =
                        *reinterpret_cast<const uint4*>(W2b + (size_t)(256 + n) * 128 + q * 8);
                }
            }
            __syncthreads();           // dst complete (+ WB c2 if c==1)

            if (c == 0) {
                // {t<128: H segmented reduce} || {t>=128: stage WB c=1}
                if (t < 128) {
                    const int d = t;
                    float a0 = 0.f; int cur = -2, e0 = 0;
                    for (int e = 0; e < TILE; ++e) {
                        int row = s_row[e];
                        if (row != cur) {
                            if (cur >= 0) {
                                bool ib = (e0 > 0) || (start[cur] == pg);
                                bool ie = true;  // row changed at e -> ended inside
                                (void)ie;
                                if (ib) Hout[(size_t)cur * 128 + d] = clip100(a0);
                                else    unsafeAtomicAdd(&Hout[(size_t)cur * 128 + d], a0);
                            }
                            cur = row; e0 = e; a0 = 0.f;
                        }
                        if (cur >= 0) a0 += bf2f(plane0[e * 132 + d]);
                    }
                    if (cur >= 0) {
                        bool ib = (e0 > 0) || (start[cur] == pg);
                        bool ie = (start[cur + 1] == pg + TILE);
                        if (ib && ie) Hout[(size_t)cur * 128 + d] = clip100(a0);
                        else          unsafeAtomicAdd(&Hout[(size_t)cur * 128 + d], a0);
                    }
                } else {
                    for (int i = t - 128; i < 128 * 16; i += 128) {
                        int n = i >> 4, q = i & 15;
                        *reinterpret_cast<uint4*>(&WB[n][q * 8]) =
                            *reinterpret_cast<const uint4*>(W2b + (size_t)(128 + n) * 128 + q * 8);
                    }
                }
                __syncthreads();
            } else if (c == 2) {
                // V segmented reduce: dv = V[vcol]*vg + unit*rg, summed per row
                if (t < 128) {
                    const int d = t;
                    float ax = 0.f, ay = 0.f, az = 0.f;
                    int cur = -2, e0 = 0;
                    for (int e = 0; e < TILE; ++e) {
                        int row = s_row[e];
                        if (row != cur) {
                            if (cur >= 0) {
                                bool ib = (e0 > 0) || (start[cur] == pg);
                                float* vo = Vout + (size_t)cur * 384 + d * 3;
                                if (ib) {
                                    vo[0] = clip100(ax); vo[1] = clip100(ay); vo[2] = clip100(az);
                                } else {
                                    unsafeAtomicAdd(vo + 0, ax);
                                    unsafeAtomicAdd(vo + 1, ay);
                                    unsafeAtomicAdd(vo + 2, az);
                                }
                            }
                            cur = row; e0 = e; ax = ay = az = 0.f;
                        }
                        if (cur >= 0) {
                            float vg = bf2f(plane1[e * 132 + d]);
                            float rg = bf2f(plane0[e * 132 + d]);
                            int vc = s_vcol[e];
                            if (vc >= 0) {
                                const float* vp = V + (size_t)vc * 384 + d * 3;
                                ax += vg * vp[0]; ay += vg * vp[1]; az += vg * vp[2];
                            }
                            ax += rg * s_unit[e][0];
                            ay += rg * s_unit[e][1];
                            az += rg * s_unit[e][2];
                        }
                    }
                    if (cur >= 0) {
                        bool ib = (e0 > 0) || (start[cur] == pg);
                        bool ie = (start[cur + 1] == pg + TILE);
                        float* vo = Vout + (size_t)cur * 384 + d * 3;
                        if (ib && ie) {
                            vo[0] = clip100(ax); vo[1] = clip100(ay); vo[2] = clip100(az);
                        } else {
                            unsafeAtomicAdd(vo + 0, ax);
                            unsafeAtomicAdd(vo + 1, ay);
                            unsafeAtomicAdd(vo + 2, az);
                        }
                    }
                }
            }
        } else {
            // MODE 0 epilogue: direct atomics (fallback)
            if (c < 2) {
                for (int i = t; i < 128 * 16; i += 256) {
                    int n = i >> 4, q = i & 15;
                    *reinterpret_cast<uint4*>(&WB[n][q * 8]) =
                        *reinterpret_cast<const uint4*>(W2b + (size_t)((c + 1) * 128 + n) * 128 + q * 8);
                }
            }
#pragma unroll
            for (int mt = 0; mt < 2; ++mt)
#pragma unroll
                for (int nt = 0; nt < 4; ++nt) {
                    int d  = nh * 64 + nt * 16 + lc;
                    float b2 = b_phi2[c * 128 + d];
                    float bm = b_msg[c * 128 + d];
#pragma unroll
                    for (int r = 0; r < 4; ++r) {
                        int e = mh * 32 + mt * 16 + lr * 4 + r;
                        float m = (p[mt][nt][r] + b2) * (g[mt][nt][r] + bm);
                        int row = s_row[e];
                        if (c == 0) {
                            if (row >= 0) unsafeAtomicAdd(&Hout[(size_t)row * 128 + d], m);
                        } else if (c == 1) {
                            vgr[mt][nt][r] = m;
                        } else if (row >= 0) {
                            float vgv = vgr[mt][nt][r];
                            int vc = s_vcol[e];
                            float vx = 0.f, vy = 0.f, vz = 0.f;
                            if (vc >= 0) {
                                const float* vp = V + ((size_t)vc * 128 + d) * 3;
                                vx = vp[0]; vy = vp[1]; vz = vp[2];
                            }
                            float* vo = Vout + ((size_t)row * 128 + d) * 3;
                            unsafeAtomicAdd(vo + 0, vx * vgv + s_unit[e][0] * m);
                            unsafeAtomicAdd(vo + 1, vy * vgv + s_unit[e][1] * m);
                            unsafeAtomicAdd(vo + 2, vz * vgv + s_unit[e][2] * m);
                        }
                    }
                }
            __syncthreads();
        }
    }
}

extern "C" void kernel_launch(void* const* d_in, const int* in_sizes, int n_in,
                              void* d_out, int out_size, void* d_ws, size_t ws_size,
                              hipStream_t stream) {
    const float* H         = (const float*)d_in[0];
    const float* V         = (const float*)d_in[1];
    const float* Z         = (const float*)d_in[2];
    const float* H2d       = (const float*)d_in[4];
    const int*   E2d_idx   = (const int*)d_in[6];
    const float* E2d_feat  = (const float*)d_in[7];
    const float* Z3d       = (const float*)d_in[8];
    const int*   Edist_idx = (const int*)d_in[10];
    const float* Edist_val = (const float*)d_in[11];
    const float* virt      = (const float*)d_in[12];
    const float* et        = (const float*)d_in[13];
    const float* W_rbf     = (const float*)d_in[14];
    const float* W_e2d     = (const float*)d_in[15];
    const float* W_i       = (const float*)d_in[16];
    const float* W_phi1    = (const float*)d_in[17];
    const float* b_phi1    = (const float*)d_in[18];
    const float* W_phi2    = (const float*)d_in[19];
    const float* b_phi2    = (const float*)d_in[20];
    const float* W_msg     = (const float*)d_in[21];
    const float* b_msg     = (const float*)d_in[22];

    ushort* nodesb  = (ushort*)d_ws;                 // 40000*128 bf16
    ushort* W1c     = nodesb + 5120000;              // (128,256)
    ushort* W2b     = W1c + 32768;                   // (384,128)
    ushort* Wmb     = W2b + 49152;                   // (384,64)
    ushort* Wib     = Wmb + 24576;                   // (128,256)
    float*  b_type  = (float*)(Wib + 32768);         // (3,128)
    ushort* featTb  = (ushort*)(b_type + 384);       // (E1N,64) bf16 = 12.8 MB
    int*    hist    = (int*)(featTb + (size_t)E1N * 64);
    int*    cursor  = hist + NN;
    int*    start   = cursor + NN;                   // NN+1
    int*    order   = start + NN + 1;                // NPAD
    int4*   metaI   = (int4*)(((size_t)(order + NPAD) + 15) & ~(size_t)15);
    float4* metaF   = (float4*)(metaI + NPAD);
    float4* metaU   = metaF + NPAD;

    size_t fixed = (size_t)((char*)(metaU + NPAD) - (char*)d_ws);
    const bool big = (ws_size >= fixed);

    float* Hout = (float*)d_out;
    float* Vout = Hout + (size_t)NN * 128;

    hipMemsetAsync(d_out, 0, (size_t)out_size * sizeof(float), stream);
    prep_kernel<<<(139648 + 255) / 256, 256, 0, stream>>>(
        W_phi1, b_phi1, W_e2d, W_rbf, W_phi2, W_msg, et, W_i,
        W1c, W2b, Wmb, b_type, Wib);
    nodes_mfma_kernel<<<(2 * NN) / 64, 256, 0, stream>>>(H, H2d, virt, Wib, nodesb);

    if (big) {
        hipMemsetAsync(hist, 0, NN * sizeof(int), stream);
        featT_kernel<<<(E1N + 63) / 64, 256, 0, stream>>>(E2d_feat, featTb);
        hist_kernel<<<(NEFF + 255) / 256, 256, 0, stream>>>(E2d_idx, Edist_idx, hist);
        scan_kernel<<<1, 1024, 0, stream>>>(hist, start, cursor);
        scatter_kernel<<<(NEFF + 255) / 256, 256, 0, stream>>>(E2d_idx, Edist_idx, cursor, order);
        meta_kernel<<<(NPAD + 255) / 256, 256, 0, stream>>>(
            order, E2d_idx, Edist_idx, Edist_val, Z, Z3d, metaI, metaF, metaU);
        edge_kernel<1><<<NBLK, 256, 0, stream>>>(
            nodesb, V, Z, Z3d, E2d_idx, E2d_feat, featTb, Edist_idx, Edist_val,
            W1c, W2b, Wmb, b_type, b_phi2, b_msg, metaI, metaF, metaU, start,
            Hout, Vout);
    } else {
        edge_kernel<0><<<NBLK, 256, 0, stream>>>(
            nodesb, V, Z, Z3d, E2d_idx, E2d_feat, featTb, Edist_idx, Edist_val,
            W1c, W2b, Wmb, b_type, b_phi2, b_msg, metaI, metaF, metaU, start,
            Hout, Vout);
    }
}

// Round 11
// 443.685 us; speedup vs baseline: 1.1551x; 1.1551x over previous
//
#include <hip/hip_runtime.h>
#include <hip/hip_bf16.h>

#define NN   20000
#define E1N  100000
#define E2N  100000
#define NEFF 220000                     /* effective edges (skip row>=n half of E3d) */
#define TILE 64
#define NBLK ((NEFF + TILE - 1) / TILE) /* 3438 */
#define NPAD (NBLK * TILE)              /* 220032 */
#define RBF_STEP   0.09523809523809523f /* 6/63 */
#define RBF_INV2W2 56.88888888888889f   /* 1/(2*(6/64)^2) */

typedef short  bf16x8 __attribute__((ext_vector_type(8)));
typedef float  f32x4  __attribute__((ext_vector_type(4)));

__device__ __forceinline__ float4 ld4(const float* p) {
    return *reinterpret_cast<const float4*>(p);
}
__device__ __forceinline__ ushort f2bf(float x) {
    __hip_bfloat16 h = __float2bfloat16(x);
    return *reinterpret_cast<ushort*>(&h);
}
__device__ __forceinline__ float bf2f(ushort u) {
    return __uint_as_float(((unsigned)u) << 16);
}
__device__ __forceinline__ float env_of(float d) {
    float x = fminf(fmaxf(d * (1.0f / 6.0f), 0.0f), 1.0f);
    return 0.5f * (__cosf(3.14159265358979f * x) + 1.0f);
}
__device__ __forceinline__ float clip100(float x) {
    return fminf(fmaxf(x, -100.f), 100.f);
}

__device__ __forceinline__ int edge_row(int eid, const int* __restrict__ E2d_idx,
                                        const int* __restrict__ Edist_idx) {
    if (eid < E1N) return E2d_idx[eid];
    if (eid < E1N + NN) return eid - E1N;
    return Edist_idx[eid - E1N - NN];
}

// ---------------- sort pipeline ----------------
__global__ __launch_bounds__(256) void hist_kernel(
    const int* __restrict__ E2d_idx, const int* __restrict__ Edist_idx,
    int* __restrict__ hist) {
    int g = blockIdx.x * 256 + threadIdx.x;
    if (g < NEFF) atomicAdd(&hist[edge_row(g, E2d_idx, Edist_idx)], 1);
}

// fast single-block scan: 256 threads x 80-element serial chunks + shuffle scan
__global__ __launch_bounds__(256) void scan_kernel(
    const int* __restrict__ hist, int* __restrict__ start, int* __restrict__ cursor) {
    __shared__ int wsum[4];
    const int t = threadIdx.x;
    const int base = t * 80;                 // 256*80 = 20480 >= NN
    int s = 0;
    for (int j = 0; j < 80; ++j) {
        int idx = base + j;
        if (idx < NN) s += hist[idx];
    }
    const int lane = t & 63, w = t >> 6;
    int v = s;
    for (int off = 1; off < 64; off <<= 1) {
        int x = __shfl_up(v, off, 64);
        if (lane >= off) v += x;
    }
    if (lane == 63) wsum[w] = v;
    __syncthreads();
    int woff = 0;
    for (int i = 0; i < w; ++i) woff += wsum[i];
    int run = woff + v - s;                  // exclusive prefix for this chunk
    for (int j = 0; j < 80; ++j) {
        int idx = base + j;
        if (idx < NN) {
            start[idx] = run;
            cursor[idx] = run;
            run += hist[idx];
        }
    }
    if (t == 255) start[NN] = run;
}

__global__ __launch_bounds__(256) void scatter_kernel(
    const int* __restrict__ E2d_idx, const int* __restrict__ Edist_idx,
    int* __restrict__ cursor, int* __restrict__ order) {
    int g = blockIdx.x * 256 + threadIdx.x;
    if (g < NEFF) {
        int r = edge_row(g, E2d_idx, Edist_idx);
        int pos = atomicAdd(&cursor[r], 1);
        order[pos] = g;
    }
}

// ---------------- meta: per-sorted-edge precompute ----------------
__global__ __launch_bounds__(256) void meta_kernel(
    const int* __restrict__ order, const int* __restrict__ E2d_idx,
    const int* __restrict__ Edist_idx, const float* __restrict__ Edist_val,
    const float* __restrict__ Z, const float* __restrict__ Z3d,
    int4* __restrict__ metaI, float4* __restrict__ metaF,
    float4* __restrict__ metaU) {
    int g = blockIdx.x * 256 + threadIdx.x;
    if (g >= NPAD) return;
    int eid = (g < NEFF) ? order[g] : -1;
    int row, col, ty, e2 = 0; float dval = 0.f;
    if (eid < 0)             { ty = 1; row = -1; col = 0; }
    else if (eid < E1N)      { ty = 0; row = E2d_idx[eid]; col = E2d_idx[E1N + eid]; e2 = eid; }
    else if (eid < E1N + NN) { ty = 1; int jj = eid - E1N; row = jj; col = jj + NN; }
    else { ty = 2; int g2 = eid - E1N - NN;
           row = Edist_idx[g2]; col = Edist_idx[E2N + g2]; dval = Edist_val[g2]; }
    int rs = (row < 0) ? 0 : row;
    float prx = Z[rs * 3], pry = Z[rs * 3 + 1], prz = Z[rs * 3 + 2];
    float pcx, pcy, pcz;
    if (col < NN) { pcx = Z[col * 3]; pcy = Z[col * 3 + 1]; pcz = Z[col * 3 + 2]; }
    else { int c = col - NN; pcx = Z3d[c * 3]; pcy = Z3d[c * 3 + 1]; pcz = Z3d[c * 3 + 2]; }
    float dx = prx - pcx, dy = pry - pcy, dz = prz - pcz;
    float dist = sqrtf(dx * dx + dy * dy + dz * dz + 1e-8f);
    float inv = 1.0f / dist;
    int vcol = (col < NN) ? col : -1;
    metaI[g] = make_int4(col, row, ty, e2);
    metaF[g] = make_float4(dist, dval, env_of(dist), env_of(dval));
    metaU[g] = (row >= 0)
        ? make_float4(dx * inv, dy * inv, dz * inv, __int_as_float(vcol))
        : make_float4(0.f, 0.f, 0.f, __int_as_float(-1));
}

// ---------------- prep: folded/bf16 weights (+ Wib for nodes MFMA) ----------------
__global__ __launch_bounds__(256) void prep_kernel(
    const float* __restrict__ W_phi1, const float* __restrict__ b_phi1,
    const float* __restrict__ W_e2d, const float* __restrict__ W_rbf,
    const float* __restrict__ W_phi2, const float* __restrict__ W_msg,
    const float* __restrict__ et, const float* __restrict__ W_i,
    ushort* __restrict__ W1c, ushort* __restrict__ W2b,
    ushort* __restrict__ Wmb, float* __restrict__ b_type,
    ushort* __restrict__ Wib) {
    int g = blockIdx.x * 256 + threadIdx.x;
    if (g < 32768) {
        int n = g >> 8, k = g & 255;
        float v;
        if (k < 128) v = W_phi1[n * 288 + k];
        else {
            int kk = k - 128;
            const float* Wsel = (kk < 64) ? W_e2d : W_rbf;  // both (128,64)
            int j = kk & 63;
            float s = 0.f;
            for (int a = 0; a < 128; ++a) s += W_phi1[n * 288 + 128 + a] * Wsel[a * 64 + j];
            v = s;
        }
        W1c[n * 256 + k] = f2bf(v);
    } else if (g < 81920) {
        int q = g - 32768; W2b[q] = f2bf(W_phi2[q]);
    } else if (g < 106496) {
        int q = g - 81920; Wmb[q] = f2bf(W_msg[q]);
    } else if (g < 106880) {
        int q = g - 106496; int ty = q >> 7, n = q & 127;
        float s = b_phi1[n];
        for (int a = 0; a < 32; ++a) s += W_phi1[n * 288 + 256 + a] * et[ty * 32 + a];
        b_type[q] = s;
    } else if (g < 139648) {
        int q = g - 106880; Wib[q] = f2bf(W_i[q]);
    }
}

// ---------------- featT: transpose E2d_feat (64,E1N) -> bf16 (E1N,64) ----------------
__global__ __launch_bounds__(256) void featT_kernel(
    const float* __restrict__ feat, ushort* __restrict__ featTb) {
    __shared__ float tile[64][65];
    const int t = threadIdx.x;
    const int cbase = blockIdx.x * 64;
    for (int i = t; i < 64 * 64; i += 256) {
        int k = i >> 6, e = i & 63;
        tile[k][e] = (cbase + e < E1N) ? feat[(size_t)k * E1N + cbase + e] : 0.f;
    }
    __syncthreads();
    for (int i = t; i < 64 * 64; i += 256) {
        int e = i >> 6, k = i & 63;
        if (cbase + e < E1N) featTb[(size_t)(cbase + e) * 64 + k] = f2bf(tile[k][e]);
    }
}

// ---------------- nodes (MFMA) ----------------
__global__ __launch_bounds__(256, 2) void nodes_mfma_kernel(
    const float* __restrict__ H, const float* __restrict__ H2d,
    const float* __restrict__ virt, const ushort* __restrict__ Wib,
    ushort* __restrict__ nodesb) {
    __shared__ ushort A[64][264];
    __shared__ ushort WB[128][132];

    const int t = threadIdx.x;
    const int gbase = blockIdx.x * 64;

    for (int i = t; i < 64 * 64; i += 256) {
        int e = i >> 6, q = i & 63;
        int row = gbase + e;
        float4 v;
        if (q < 32)          v = ld4(H + (size_t)((row < NN) ? row : row - NN) * 128 + q * 4);
        else if (row < NN)   v = ld4(H2d + (size_t)row * 128 + (q - 32) * 4);
        else                 v = ld4(virt + (q - 32) * 4);
        ushort tmp[4] = {f2bf(v.x), f2bf(v.y), f2bf(v.z), f2bf(v.w)};
        *reinterpret_cast<uint2*>(&A[e][q * 4]) = *reinterpret_cast<const uint2*>(tmp);
    }
    for (int i = t; i < 128 * 16; i += 256) {
        int n = i >> 4, q = i & 15;
        *reinterpret_cast<uint4*>(&WB[n][q * 8]) =
            *reinterpret_cast<const uint4*>(Wib + (size_t)n * 256 + q * 8);
    }
    __syncthreads();

    const int w  = t >> 6, lane = t & 63;
    const int mh = w >> 1, nh = w & 1;
    const int lr = lane >> 4, lc = lane & 15;
    const int ar0 = mh * 32 + lc;

    f32x4 acc[2][4];
#pragma unroll
    for (int mt = 0; mt < 2; ++mt)
#pragma unroll
        for (int nt = 0; nt < 4; ++nt) acc[mt][nt] = (f32x4){0.f, 0.f, 0.f, 0.f};
#pragma unroll
    for (int ks = 0; ks < 4; ++ks) {
        bf16x8 a0 = *reinterpret_cast<const bf16x8*>(&A[ar0][ks * 32 + lr * 8]);
        bf16x8 a1 = *reinterpret_cast<const bf16x8*>(&A[ar0 + 16][ks * 32 + lr * 8]);
#pragma unroll
        for (int nt = 0; nt < 4; ++nt) {
            int n = nh * 64 + nt * 16 + lc;
            bf16x8 b = *reinterpret_cast<const bf16x8*>(&WB[n][ks * 32 + lr * 8]);
            acc[0][nt] = __builtin_amdgcn_mfma_f32_16x16x32_bf16(a0, b, acc[0][nt], 0, 0, 0);
            acc[1][nt] = __builtin_amdgcn_mfma_f32_16x16x32_bf16(a1, b, acc[1][nt], 0, 0, 0);
        }
    }
    __syncthreads();
    for (int i = t; i < 128 * 16; i += 256) {
        int n = i >> 4, q = i & 15;
        *reinterpret_cast<uint4*>(&WB[n][q * 8]) =
            *reinterpret_cast<const uint4*>(Wib + (size_t)n * 256 + 128 + q * 8);
    }
    __syncthreads();
#pragma unroll
    for (int ks = 4; ks < 8; ++ks) {
        bf16x8 a0 = *reinterpret_cast<const bf16x8*>(&A[ar0][ks * 32 + lr * 8]);
        bf16x8 a1 = *reinterpret_cast<const bf16x8*>(&A[ar0 + 16][ks * 32 + lr * 8]);
#pragma unroll
        for (int nt = 0; nt < 4; ++nt) {
            int n = nh * 64 + nt * 16 + lc;
            bf16x8 b = *reinterpret_cast<const bf16x8*>(&WB[n][(ks - 4) * 32 + lr * 8]);
            acc[0][nt] = __builtin_amdgcn_mfma_f32_16x16x32_bf16(a0, b, acc[0][nt], 0, 0, 0);
            acc[1][nt] = __builtin_amdgcn_mfma_f32_16x16x32_bf16(a1, b, acc[1][nt], 0, 0, 0);
        }
    }
#pragma unroll
    for (int mt = 0; mt < 2; ++mt)
#pragma unroll
        for (int nt = 0; nt < 4; ++nt)
#pragma unroll
            for (int r = 0; r < 4; ++r) {
                int e  = mh * 32 + mt * 16 + lr * 4 + r;
                int ch = nh * 64 + nt * 16 + lc;
                nodesb[(size_t)(gbase + e) * 128 + ch] = f2bf(acc[mt][nt][r]);
            }
}

// ---------------- edge1: MFMA pipeline, in-register A-fragments, 3 blocks/CU ----------------
__global__ __launch_bounds__(256, 3) void edge1_kernel(
    const ushort* __restrict__ nodesb, const ushort* __restrict__ featTb,
    const ushort* __restrict__ W1c, const ushort* __restrict__ W2b,
    const ushort* __restrict__ Wmb, const float* __restrict__ b_type,
    const float* __restrict__ b_phi2, const float* __restrict__ b_msg,
    const int4* __restrict__ metaI, const float4* __restrict__ metaF,
    ushort* __restrict__ payloadM) {

    // flat LDS 53504 B: WB [0,16896) stride132 | HM [16896,25600) stride136
    // | s_bt f32[384] | s_col | s_ty | s_e2
    __shared__ ushort sm[26752];
    ushort* WB   = sm;
    ushort* HM   = sm + 16896;
    float*  s_bt = (float*)(sm + 25600);
    int*    s_col= (int*)(sm + 26368);
    int*    s_ty = (int*)(sm + 26496);
    int*    s_e2 = (int*)(sm + 26624);

    const int t = threadIdx.x;
    const int gbase = blockIdx.x * TILE;

    if (t < TILE) {
        int4 mi = metaI[gbase + t];
        s_col[t] = mi.x; s_ty[t] = mi.z; s_e2[t] = mi.w;
    }
    for (int i = t; i < 384; i += 256) s_bt[i] = b_type[i];
    for (int i = t; i < 128 * 16; i += 256) {      // WB <- W1c[:, 0:128]
        int n = i >> 4, q = i & 15;
        *reinterpret_cast<uint4*>(WB + n * 132 + q * 8) =
            *reinterpret_cast<const uint4*>(W1c + (size_t)n * 256 + q * 8);
    }
    __syncthreads();

    const int w  = t >> 6, lane = t & 63;
    const int mh = w >> 1, nh = w & 1;
    const int lr = lane >> 4, lc = lane & 15;
    const int ar0 = mh * 32 + lc;

    const int colA = s_col[ar0],      colB = s_col[ar0 + 16];
    const int tyA  = s_ty[ar0],       tyB  = s_ty[ar0 + 16];
    const int e2A  = s_e2[ar0],       e2B  = s_e2[ar0 + 16];
    const float4 mfA = metaF[gbase + ar0];
    const float4 mfB = metaF[gbase + ar0 + 16];

    // ---- A-fragments in registers ----
    bf16x8 a0[8], a1[8];
    const bf16x8 zz = {0, 0, 0, 0, 0, 0, 0, 0};
#pragma unroll
    for (int ks = 0; ks < 4; ++ks) {               // left 128: nodes[col]
        a0[ks] = *reinterpret_cast<const bf16x8*>(nodesb + (size_t)colA * 128 + ks * 32 + lr * 8);
        a1[ks] = *reinterpret_cast<const bf16x8*>(nodesb + (size_t)colB * 128 + ks * 32 + lr * 8);
    }
#pragma unroll
    for (int ks = 4; ks < 6; ++ks) {               // k 128..191: featT (ty0) else 0
        bf16x8 fA = *reinterpret_cast<const bf16x8*>(featTb + (size_t)e2A * 64 + (ks - 4) * 32 + lr * 8);
        bf16x8 fB = *reinterpret_cast<const bf16x8*>(featTb + (size_t)e2B * 64 + (ks - 4) * 32 + lr * 8);
        a0[ks] = (tyA == 0) ? fA : zz;
        a1[ks] = (tyB == 0) ? fB : zz;
    }
#pragma unroll
    for (int ks = 6; ks < 8; ++ks) {               // k 192..255: rbf(dval) (ty2) else 0
#pragma unroll
        for (int j = 0; j < 8; ++j) {
            float cc = (float)((ks - 6) * 32 + lr * 8 + j) * RBF_STEP;
            float tA = mfA.y - cc, tB = mfB.y - cc;
            ushort vA = f2bf(__expf(-tA * tA * RBF_INV2W2) * mfA.w);
            ushort vB = f2bf(__expf(-tB * tB * RBF_INV2W2) * mfB.w);
            a0[ks][j] = (tyA == 2) ? (short)vA : (short)0;
            a1[ks][j] = (tyB == 2) ? (short)vB : (short)0;
        }
    }
    // wd A-fragments: rbf(dist)
    bf16x8 ra0[2], ra1[2];
#pragma unroll
    for (int ks = 0; ks < 2; ++ks)
#pragma unroll
        for (int j = 0; j < 8; ++j) {
            float cc = (float)(ks * 32 + lr * 8 + j) * RBF_STEP;
            float tA = mfA.x - cc, tB = mfB.x - cc;
            ra0[ks][j] = (short)f2bf(__expf(-tA * tA * RBF_INV2W2) * mfA.z);
            ra1[ks][j] = (short)f2bf(__expf(-tB * tB * RBF_INV2W2) * mfB.z);
        }

    // ---- phi1: K=256 in two WB halves ----
    f32x4 acc[2][4];
#pragma unroll
    for (int mt = 0; mt < 2; ++mt)
#pragma unroll
        for (int nt = 0; nt < 4; ++nt) acc[mt][nt] = (f32x4){0.f, 0.f, 0.f, 0.f};
#pragma unroll
    for (int ks = 0; ks < 4; ++ks) {
#pragma unroll
        for (int nt = 0; nt < 4; ++nt) {
            int n = nh * 64 + nt * 16 + lc;
            bf16x8 b = *reinterpret_cast<const bf16x8*>(WB + n * 132 + ks * 32 + lr * 8);
            acc[0][nt] = __builtin_amdgcn_mfma_f32_16x16x32_bf16(a0[ks], b, acc[0][nt], 0, 0, 0);
            acc[1][nt] = __builtin_amdgcn_mfma_f32_16x16x32_bf16(a1[ks], b, acc[1][nt], 0, 0, 0);
        }
    }
    __syncthreads();
    for (int i = t; i < 128 * 16; i += 256) {      // WB <- W1c[:, 128:256]
        int n = i >> 4, q = i & 15;
        *reinterpret_cast<uint4*>(WB + n * 132 + q * 8) =
            *reinterpret_cast<const uint4*>(W1c + (size_t)n * 256 + 128 + q * 8);
    }
    __syncthreads();
#pragma unroll
    for (int ks = 4; ks < 8; ++ks) {
#pragma unroll
        for (int nt = 0; nt < 4; ++nt) {
            int n = nh * 64 + nt * 16 + lc;
            bf16x8 b = *reinterpret_cast<const bf16x8*>(WB + n * 132 + (ks - 4) * 32 + lr * 8);
            acc[0][nt] = __builtin_amdgcn_mfma_f32_16x16x32_bf16(a0[ks], b, acc[0][nt], 0, 0, 0);
            acc[1][nt] = __builtin_amdgcn_mfma_f32_16x16x32_bf16(a1[ks], b, acc[1][nt], 0, 0, 0);
        }
    }
    __syncthreads();

    // ---- silu -> HM(hid); stage WB <- W2b c=0 ----
#pragma unroll
    for (int mt = 0; mt < 2; ++mt)
#pragma unroll
        for (int nt = 0; nt < 4; ++nt)
#pragma unroll
            for (int r = 0; r < 4; ++r) {
                int e  = mh * 32 + mt * 16 + lr * 4 + r;
                int ch = nh * 64 + nt * 16 + lc;
                float x = acc[mt][nt][r] + s_bt[s_ty[e] * 128 + ch];
                HM[e * 136 + ch] = f2bf(x / (1.0f + __expf(-x)));
            }
    for (int i = t; i < 128 * 16; i += 256) {
        int n = i >> 4, q = i & 15;
        *reinterpret_cast<uint4*>(WB + n * 132 + q * 8) =
            *reinterpret_cast<const uint4*>(W2b + (size_t)n * 128 + q * 8);
    }
    __syncthreads();

    // ---- hoist hid A-fragments ----
    bf16x8 ha0[4], ha1[4];
#pragma unroll
    for (int ks = 0; ks < 4; ++ks) {
        ha0[ks] = *reinterpret_cast<const bf16x8*>(HM + ar0 * 136 + ks * 32 + lr * 8);
        ha1[ks] = *reinterpret_cast<const bf16x8*>(HM + (ar0 + 16) * 136 + ks * 32 + lr * 8);
    }

    // ---- phi2 + wd in 3 channel-chunks; m = phi*wd -> HM -> payload ----
#pragma unroll
    for (int c = 0; c < 3; ++c) {
        f32x4 p[2][4], g[2][4];
#pragma unroll
        for (int mt = 0; mt < 2; ++mt)
#pragma unroll
            for (int nt = 0; nt < 4; ++nt) {
                p[mt][nt] = (f32x4){0.f, 0.f, 0.f, 0.f};
                g[mt][nt] = (f32x4){0.f, 0.f, 0.f, 0.f};
            }
#pragma unroll
        for (int ks = 0; ks < 4; ++ks) {
#pragma unroll
            for (int nt = 0; nt < 4; ++nt) {
                int n = nh * 64 + nt * 16 + lc;
                bf16x8 b = *reinterpret_cast<const bf16x8*>(WB + n * 132 + ks * 32 + lr * 8);
                p[0][nt] = __builtin_amdgcn_mfma_f32_16x16x32_bf16(ha0[ks], b, p[0][nt], 0, 0, 0);
                p[1][nt] = __builtin_amdgcn_mfma_f32_16x16x32_bf16(ha1[ks], b, p[1][nt], 0, 0, 0);
            }
        }
#pragma unroll
        for (int ks = 0; ks < 2; ++ks) {
#pragma unroll
            for (int nt = 0; nt < 4; ++nt) {
                int n = c * 128 + nh * 64 + nt * 16 + lc;
                bf16x8 b = *reinterpret_cast<const bf16x8*>(Wmb + (size_t)n * 64 + ks * 32 + lr * 8);
                g[0][nt] = __builtin_amdgcn_mfma_f32_16x16x32_bf16(ra0[ks], b, g[0][nt], 0, 0, 0);
                g[1][nt] = __builtin_amdgcn_mfma_f32_16x16x32_bf16(ra1[ks], b, g[1][nt], 0, 0, 0);
            }
        }
        __syncthreads();               // WB reads for this c done; prev copy done
#pragma unroll
        for (int mt = 0; mt < 2; ++mt)
#pragma unroll
            for (int nt = 0; nt < 4; ++nt) {
                int d  = nh * 64 + nt * 16 + lc;
                float b2 = b_phi2[c * 128 + d];
                float bm = b_msg[c * 128 + d];
#pragma unroll
                for (int r = 0; r < 4; ++r) {
                    int e = mh * 32 + mt * 16 + lr * 4 + r;
                    HM[e * 136 + d] = f2bf((p[mt][nt][r] + b2) * (g[mt][nt][r] + bm));
                }
            }
        if (c < 2) {                   // stage next c's W2b slice
            for (int i = t; i < 128 * 16; i += 256) {
                int n = i >> 4, q = i & 15;
                *reinterpret_cast<uint4*>(WB + n * 132 + q * 8) =
                    *reinterpret_cast<const uint4*>(W2b + (size_t)((c + 1) * 128 + n) * 128 + q * 8);
            }
        }
        __syncthreads();               // HM complete + WB staged
        // coalesced copy HM[64][136] -> payloadM (8B units)
        for (int i = t; i < 2048; i += 256) {
            int e = i >> 5, q = i & 31;
            *reinterpret_cast<uint2*>(payloadM + (size_t)(gbase + e) * 384 + c * 128 + q * 4) =
                *reinterpret_cast<const uint2*>(HM + e * 136 + q * 4);
        }
    }
}

// ---------------- fallback: monolithic atomic edge kernel ----------------
__global__ __launch_bounds__(256, 2) void edge0_kernel(
    const ushort* __restrict__ nodesb, const float* __restrict__ V,
    const float* __restrict__ Z, const float* __restrict__ Z3d,
    const int* __restrict__ E2d_idx, const float* __restrict__ E2d_feat,
    const int* __restrict__ Edist_idx, const float* __restrict__ Edist_val,
    const ushort* __restrict__ W1c, const ushort* __restrict__ W2b,
    const ushort* __restrict__ Wmb, const float* __restrict__ b_type,
    const float* __restrict__ b_phi2, const float* __restrict__ b_msg,
    float* __restrict__ Hout, float* __restrict__ Vout) {

    __shared__ ushort A1[TILE][264];
    __shared__ float  s_bt[3][128];
    __shared__ int    s_row[TILE], s_col[TILE], s_ty[TILE], s_e2[TILE], s_vcol[TILE];
    __shared__ float  s_dist[TILE], s_dval[TILE], s_env[TILE], s_env2[TILE];
    __shared__ float  s_unit[TILE][3];
    ushort (*hid)[136] = reinterpret_cast<ushort(*)[136]>(&A1[0][0]);

    const int t = threadIdx.x;
    const int gbase = blockIdx.x * TILE;
    if (t < TILE) {
        int gpos = gbase + t;
        int eid = (gpos < NEFF) ? gpos : -1;
        int row, col, ty, e2 = 0; float dval = 0.f;
        if (eid < 0)             { ty = 1; row = -1; col = 0; }
        else if (eid < E1N)      { ty = 0; row = E2d_idx[eid]; col = E2d_idx[E1N + eid]; e2 = eid; }
        else if (eid < E1N + NN) { ty = 1; int jj = eid - E1N; row = jj; col = jj + NN; }
        else { ty = 2; int g2 = eid - E1N - NN;
               row = Edist_idx[g2]; col = Edist_idx[E2N + g2]; dval = Edist_val[g2]; }
        int rs = (row < 0) ? 0 : row;
        float prx = Z[rs * 3], pry = Z[rs * 3 + 1], prz = Z[rs * 3 + 2];
        float pcx, pcy, pcz;
        if (col < NN) { pcx = Z[col * 3]; pcy = Z[col * 3 + 1]; pcz = Z[col * 3 + 2]; }
        else { int c = col - NN; pcx = Z3d[c * 3]; pcy = Z3d[c * 3 + 1]; pcz = Z3d[c * 3 + 2]; }
        float dx = prx - pcx, dy = pry - pcy, dz = prz - pcz;
        float dist = sqrtf(dx * dx + dy * dy + dz * dz + 1e-8f);
        float inv = 1.0f / dist;
        s_row[t] = row; s_col[t] = col; s_ty[t] = ty; s_e2[t] = e2;
        s_vcol[t] = (col < NN) ? col : -1;
        s_unit[t][0] = dx * inv; s_unit[t][1] = dy * inv; s_unit[t][2] = dz * inv;
        s_dist[t] = dist; s_dval[t] = dval;
        s_env[t] = env_of(dist); s_env2[t] = env_of(dval);
    }
    for (int i = t; i < 384; i += 256) ((float*)s_bt)[i] = b_type[i];
    __syncthreads();

    for (int i = t; i < TILE * 16; i += 256) {
        int e = i >> 4, q = i & 15;
        *reinterpret_cast<uint4*>(&A1[e][q * 8]) =
            *reinterpret_cast<const uint4*>(nodesb + (size_t)s_col[e] * 128 + q * 8);
    }
    for (int i = t; i < TILE * 128; i += 256) {
        int k = i >> 6, e = i & 63;
        int ty = s_ty[e];
        float v = 0.f;
        if (ty == 0) { if (k < 64) v = E2d_feat[(size_t)k * E1N + s_e2[e]]; }
        else if (ty == 2) {
            if (k >= 64) {
                float dd = s_dval[e] - (float)(k - 64) * RBF_STEP;
                v = __expf(-dd * dd * RBF_INV2W2) * s_env2[e];
            }
        }
        A1[e][128 + k] = f2bf(v);
    }
    __syncthreads();

    const int w  = t >> 6, lane = t & 63;
    const int mh = w >> 1, nh = w & 1;
    const int lr = lane >> 4, lc = lane & 15;
    const int ar0 = mh * 32 + lc;

    bf16x8 ra0[2], ra1[2];
    {
        float dA = s_dist[ar0],      eA = s_env[ar0];
        float dB = s_dist[ar0 + 16], eB = s_env[ar0 + 16];
#pragma unroll
        for (int ks = 0; ks < 2; ++ks)
#pragma unroll
            for (int j = 0; j < 8; ++j) {
                float c  = (float)(ks * 32 + lr * 8 + j) * RBF_STEP;
                float tA = dA - c, tB = dB - c;
                ra0[ks][j] = (short)f2bf(__expf(-tA * tA * RBF_INV2W2) * eA);
                ra1[ks][j] = (short)f2bf(__expf(-tB * tB * RBF_INV2W2) * eB);
            }
    }

    f32x4 acc[2][4];
#pragma unroll
    for (int mt = 0; mt < 2; ++mt)
#pragma unroll
        for (int nt = 0; nt < 4; ++nt) acc[mt][nt] = (f32x4){0.f, 0.f, 0.f, 0.f};
#pragma unroll
    for (int ks = 0; ks < 8; ++ks) {
        bf16x8 a0 = *reinterpret_cast<const bf16x8*>(&A1[ar0][ks * 32 + lr * 8]);
        bf16x8 a1 = *reinterpret_cast<const bf16x8*>(&A1[ar0 + 16][ks * 32 + lr * 8]);
#pragma unroll
        for (int nt = 0; nt < 4; ++nt) {
            int n = nh * 64 + nt * 16 + lc;
            bf16x8 b = *reinterpret_cast<const bf16x8*>(W1c + (size_t)n * 256 + ks * 32 + lr * 8);
            acc[0][nt] = __builtin_amdgcn_mfma_f32_16x16x32_bf16(a0, b, acc[0][nt], 0, 0, 0);
            acc[1][nt] = __builtin_amdgcn_mfma_f32_16x16x32_bf16(a1, b, acc[1][nt], 0, 0, 0);
        }
    }
    __syncthreads();
#pragma unroll
    for (int mt = 0; mt < 2; ++mt)
#pragma unroll
        for (int nt = 0; nt < 4; ++nt)
#pragma unroll
            for (int r = 0; r < 4; ++r) {
                int e  = mh * 32 + mt * 16 + lr * 4 + r;
                int ch = nh * 64 + nt * 16 + lc;
                float x = acc[mt][nt][r] + s_bt[s_ty[e]][ch];
                hid[e][ch] = f2bf(x / (1.0f + __expf(-x)));
            }
    __syncthreads();

    f32x4 vgr[2][4];
#pragma unroll
    for (int c = 0; c < 3; ++c) {
        f32x4 p[2][4], g[2][4];
#pragma unroll
        for (int mt = 0; mt < 2; ++mt)
#pragma unroll
            for (int nt = 0; nt < 4; ++nt) {
                p[mt][nt] = (f32x4){0.f, 0.f, 0.f, 0.f};
                g[mt][nt] = (f32x4){0.f, 0.f, 0.f, 0.f};
            }
#pragma unroll
        for (int ks = 0; ks < 4; ++ks) {
            bf16x8 a0 = *reinterpret_cast<const bf16x8*>(&hid[ar0][ks * 32 + lr * 8]);
            bf16x8 a1 = *reinterpret_cast<const bf16x8*>(&hid[ar0 + 16][ks * 32 + lr * 8]);
#pragma unroll
            for (int nt = 0; nt < 4; ++nt) {
                int n = c * 128 + nh * 64 + nt * 16 + lc;
                bf16x8 b = *reinterpret_cast<const bf16x8*>(W2b + (size_t)n * 128 + ks * 32 + lr * 8);
                p[0][nt] = __builtin_amdgcn_mfma_f32_16x16x32_bf16(a0, b, p[0][nt], 0, 0, 0);
                p[1][nt] = __builtin_amdgcn_mfma_f32_16x16x32_bf16(a1, b, p[1][nt], 0, 0, 0);
            }
        }
#pragma unroll
        for (int ks = 0; ks < 2; ++ks) {
#pragma unroll
            for (int nt = 0; nt < 4; ++nt) {
                int n = c * 128 + nh * 64 + nt * 16 + lc;
                bf16x8 b = *reinterpret_cast<const bf16x8*>(Wmb + (size_t)n * 64 + ks * 32 + lr * 8);
                g[0][nt] = __builtin_amdgcn_mfma_f32_16x16x32_bf16(ra0[ks], b, g[0][nt], 0, 0, 0);
                g[1][nt] = __builtin_amdgcn_mfma_f32_16x16x32_bf16(ra1[ks], b, g[1][nt], 0, 0, 0);
            }
        }
#pragma unroll
        for (int mt = 0; mt < 2; ++mt)
#pragma unroll
            for (int nt = 0; nt < 4; ++nt) {
                int d  = nh * 64 + nt * 16 + lc;
                float b2 = b_phi2[c * 128 + d];
                float bm = b_msg[c * 128 + d];
#pragma unroll
                for (int r = 0; r < 4; ++r) {
                    int e = mh * 32 + mt * 16 + lr * 4 + r;
                    float m = (p[mt][nt][r] + b2) * (g[mt][nt][r] + bm);
                    int row = s_row[e];
                    if (c == 0) {
                        if (row >= 0) unsafeAtomicAdd(&Hout[(size_t)row * 128 + d], m);
                    } else if (c == 1) {
                        vgr[mt][nt][r] = m;
                    } else if (row >= 0) {
                        float vgv = vgr[mt][nt][r];
                        int vc = s_vcol[e];
                        float vx = 0.f, vy = 0.f, vz = 0.f;
                        if (vc >= 0) {
                            const float* vp = V + ((size_t)vc * 128 + d) * 3;
                            vx = vp[0]; vy = vp[1]; vz = vp[2];
                        }
                        float* vo = Vout + ((size_t)row * 128 + d) * 3;
                        unsafeAtomicAdd(vo + 0, vx * vgv + s_unit[e][0] * m);
                        unsafeAtomicAdd(vo + 1, vy * vgv + s_unit[e][1] * m);
                        unsafeAtomicAdd(vo + 2, vz * vgv + s_unit[e][2] * m);
                    }
                }
            }
    }
}

// ---------------- reduce: all rows, pure write (no memset needed) ----------------
__global__ __launch_bounds__(256) void reduce_kernel(
    const ushort* __restrict__ payloadM, const float4* __restrict__ metaU,
    const float* __restrict__ V, const int* __restrict__ start,
    float* __restrict__ Hout, float* __restrict__ Vout) {
    const int t = threadIdx.x;
    const int rbase = blockIdx.x * 8;
    const bool hside = (t < 128);
    const int d = hside ? t : (t - 128);
    for (int nr = 0; nr < 8; ++nr) {
        int r = rbase + nr;
        if (r >= NN) return;
        int a = start[r], b = start[r + 1];
        int n = b - a;
        if (hside) {
            const ushort* base = payloadM + (size_t)a * 384 + d;
            float a0 = 0.f, a1 = 0.f, a2 = 0.f, a3 = 0.f;
            int i = 0;
            for (; i + 4 <= n; i += 4) {
                a0 += bf2f(base[(size_t)i * 384]);
                a1 += bf2f(base[(size_t)(i + 1) * 384]);
                a2 += bf2f(base[(size_t)(i + 2) * 384]);
                a3 += bf2f(base[(size_t)(i + 3) * 384]);
            }
            for (; i < n; ++i) a0 += bf2f(base[(size_t)i * 384]);
            Hout[(size_t)r * 128 + d] = clip100((a0 + a1) + (a2 + a3));
        } else {
            const ushort* base = payloadM + (size_t)a * 384;
            const float4* ub = metaU + a;
            float ax = 0.f, ay = 0.f, az = 0.f;
            float bx = 0.f, by = 0.f, bz = 0.f;
            int i = 0;
            for (; i + 2 <= n; i += 2) {
                const ushort* pm0 = base + (size_t)i * 384;
                const ushort* pm1 = base + (size_t)(i + 1) * 384;
                float vg0 = bf2f(pm0[128 + d]), rg0 = bf2f(pm0[256 + d]);
                float vg1 = bf2f(pm1[128 + d]), rg1 = bf2f(pm1[256 + d]);
                float4 u0 = ub[i];
                float4 u1 = ub[i + 1];
                int vc0 = __float_as_int(u0.w);
                int vc1 = __float_as_int(u1.w);
                if (vc0 >= 0) {
                    const float* vp = V + (size_t)vc0 * 384 + d * 3;
                    ax += vg0 * vp[0]; ay += vg0 * vp[1]; az += vg0 * vp[2];
                }
                if (vc1 >= 0) {
                    const float* vp = V + (size_t)vc1 * 384 + d * 3;
                    bx += vg1 * vp[0]; by += vg1 * vp[1]; bz += vg1 * vp[2];
                }
                ax += rg0 * u0.x; ay += rg0 * u0.y; az += rg0 * u0.z;
                bx += rg1 * u1.x; by += rg1 * u1.y; bz += rg1 * u1.z;
            }
            if (i < n) {
                const ushort* pm0 = base + (size_t)i * 384;
                float vg0 = bf2f(pm0[128 + d]), rg0 = bf2f(pm0[256 + d]);
                float4 u0 = ub[i];
                int vc0 = __float_as_int(u0.w);
                if (vc0 >= 0) {
                    const float* vp = V + (size_t)vc0 * 384 + d * 3;
                    ax += vg0 * vp[0]; ay += vg0 * vp[1]; az += vg0 * vp[2];
                }
                ax += rg0 * u0.x; ay += rg0 * u0.y; az += rg0 * u0.z;
            }
            float* vo = Vout + (size_t)r * 384 + d * 3;
            vo[0] = clip100(ax + bx);
            vo[1] = clip100(ay + by);
            vo[2] = clip100(az + bz);
        }
    }
}

extern "C" void kernel_launch(void* const* d_in, const int* in_sizes, int n_in,
                              void* d_out, int out_size, void* d_ws, size_t ws_size,
                              hipStream_t stream) {
    const float* H         = (const float*)d_in[0];
    const float* V         = (const float*)d_in[1];
    const float* Z         = (const float*)d_in[2];
    const float* H2d       = (const float*)d_in[4];
    const int*   E2d_idx   = (const int*)d_in[6];
    const float* E2d_feat  = (const float*)d_in[7];
    const float* Z3d       = (const float*)d_in[8];
    const int*   Edist_idx = (const int*)d_in[10];
    const float* Edist_val = (const float*)d_in[11];
    const float* virt      = (const float*)d_in[12];
    const float* et        = (const float*)d_in[13];
    const float* W_rbf     = (const float*)d_in[14];
    const float* W_e2d     = (const float*)d_in[15];
    const float* W_i       = (const float*)d_in[16];
    const float* W_phi1    = (const float*)d_in[17];
    const float* b_phi1    = (const float*)d_in[18];
    const float* W_phi2    = (const float*)d_in[19];
    const float* b_phi2    = (const float*)d_in[20];
    const float* W_msg     = (const float*)d_in[21];
    const float* b_msg     = (const float*)d_in[22];

    ushort* nodesb  = (ushort*)d_ws;                 // 40000*128 bf16
    ushort* W1c     = nodesb + 5120000;              // (128,256)
    ushort* W2b     = W1c + 32768;                   // (384,128)
    ushort* Wmb     = W2b + 49152;                   // (384,64)
    ushort* Wib     = Wmb + 24576;                   // (128,256)
    float*  b_type  = (float*)(Wib + 32768);         // (3,128)
    ushort* featTb  = (ushort*)(b_type + 384);       // (E1N,64) bf16
    int*    hist    = (int*)(featTb + (size_t)E1N * 64);
    int*    cursor  = hist + NN;
    int*    start   = cursor + NN;                   // NN+1
    int*    order   = start + NN + 1;                // NPAD
    int4*   metaI   = (int4*)(((size_t)(order + NPAD) + 15) & ~(size_t)15);
    float4* metaF   = (float4*)(metaI + NPAD);
    float4* metaU   = metaF + NPAD;

    size_t fixed = (size_t)((char*)(metaU + NPAD) - (char*)d_ws);
    size_t poff  = (fixed + 255) & ~(size_t)255;
    size_t need  = poff + (size_t)NPAD * 384 * sizeof(ushort);   // full bf16 payload
    const bool big = (ws_size >= need);
    ushort* payloadM = (ushort*)((char*)d_ws + poff);

    float* Hout = (float*)d_out;
    float* Vout = Hout + (size_t)NN * 128;

    prep_kernel<<<(139648 + 255) / 256, 256, 0, stream>>>(
        W_phi1, b_phi1, W_e2d, W_rbf, W_phi2, W_msg, et, W_i,
        W1c, W2b, Wmb, b_type, Wib);
    nodes_mfma_kernel<<<(2 * NN) / 64, 256, 0, stream>>>(H, H2d, virt, Wib, nodesb);

    if (big) {
        hipMemsetAsync(hist, 0, NN * sizeof(int), stream);
        featT_kernel<<<(E1N + 63) / 64, 256, 0, stream>>>(E2d_feat, featTb);
        hist_kernel<<<(NEFF + 255) / 256, 256, 0, stream>>>(E2d_idx, Edist_idx, hist);
        scan_kernel<<<1, 256, 0, stream>>>(hist, start, cursor);
        scatter_kernel<<<(NEFF + 255) / 256, 256, 0, stream>>>(E2d_idx, Edist_idx, cursor, order);
        meta_kernel<<<(NPAD + 255) / 256, 256, 0, stream>>>(
            order, E2d_idx, Edist_idx, Edist_val, Z, Z3d, metaI, metaF, metaU);
        edge1_kernel<<<NBLK, 256, 0, stream>>>(
            nodesb, featTb, W1c, W2b, Wmb, b_type, b_phi2, b_msg,
            metaI, metaF, payloadM);
        reduce_kernel<<<(NN + 7) / 8, 256, 0, stream>>>(
            payloadM, metaU, V, start, Hout, Vout);
    } else {
        hipMemsetAsync(d_out, 0, (size_t)out_size * sizeof(float), stream);
        edge0_kernel<<<NBLK, 256, 0, stream>>>(
            nodesb, V, Z, Z3d, E2d_idx, E2d_feat, Edist_idx, Edist_val,
            W1c, W2b, Wmb, b_type, b_phi2, b_msg, Hout, Vout);
    }
}

// Round 12
// 398.172 us; speedup vs baseline: 1.2871x; 1.1143x over previous
//
#include <hip/hip_runtime.h>
#include <hip/hip_bf16.h>

#define NN   20000
#define E1N  100000
#define E2N  100000
#define NEFF 220000                     /* effective edges (skip row>=n half of E3d) */
#define TILE 64
#define NBLK ((NEFF + TILE - 1) / TILE) /* 3438 */
#define NPAD (NBLK * TILE)              /* 220032 */
#define RBF_STEP   0.09523809523809523f /* 6/63 */
#define RBF_INV2W2 56.88888888888889f   /* 1/(2*(6/64)^2) */

typedef short  bf16x8 __attribute__((ext_vector_type(8)));
typedef float  f32x4  __attribute__((ext_vector_type(4)));

__device__ __forceinline__ float4 ld4(const float* p) {
    return *reinterpret_cast<const float4*>(p);
}
__device__ __forceinline__ ushort f2bf(float x) {
    __hip_bfloat16 h = __float2bfloat16(x);
    return *reinterpret_cast<ushort*>(&h);
}
__device__ __forceinline__ float bf2f(ushort u) {
    return __uint_as_float(((unsigned)u) << 16);
}
__device__ __forceinline__ float env_of(float d) {
    float x = fminf(fmaxf(d * (1.0f / 6.0f), 0.0f), 1.0f);
    return 0.5f * (__cosf(3.14159265358979f * x) + 1.0f);
}
__device__ __forceinline__ float clip100(float x) {
    return fminf(fmaxf(x, -100.f), 100.f);
}

__device__ __forceinline__ int edge_row(int eid, const int* __restrict__ E2d_idx,
                                        const int* __restrict__ Edist_idx) {
    if (eid < E1N) return E2d_idx[eid];
    if (eid < E1N + NN) return eid - E1N;
    return Edist_idx[eid - E1N - NN];
}

// ---------------- sort pipeline ----------------
__global__ __launch_bounds__(256) void hist_kernel(
    const int* __restrict__ E2d_idx, const int* __restrict__ Edist_idx,
    int* __restrict__ hist) {
    int g = blockIdx.x * 256 + threadIdx.x;
    if (g < NEFF) atomicAdd(&hist[edge_row(g, E2d_idx, Edist_idx)], 1);
}

// fast single-block scan: 256 threads x 80-element serial chunks + shuffle scan
__global__ __launch_bounds__(256) void scan_kernel(
    const int* __restrict__ hist, int* __restrict__ start, int* __restrict__ cursor) {
    __shared__ int wsum[4];
    const int t = threadIdx.x;
    const int base = t * 80;                 // 256*80 = 20480 >= NN
    int s = 0;
    for (int j = 0; j < 80; ++j) {
        int idx = base + j;
        if (idx < NN) s += hist[idx];
    }
    const int lane = t & 63, w = t >> 6;
    int v = s;
    for (int off = 1; off < 64; off <<= 1) {
        int x = __shfl_up(v, off, 64);
        if (lane >= off) v += x;
    }
    if (lane == 63) wsum[w] = v;
    __syncthreads();
    int woff = 0;
    for (int i = 0; i < w; ++i) woff += wsum[i];
    int run = woff + v - s;                  // exclusive prefix for this chunk
    for (int j = 0; j < 80; ++j) {
        int idx = base + j;
        if (idx < NN) {
            start[idx] = run;
            cursor[idx] = run;
            run += hist[idx];
        }
    }
    if (t == 255) start[NN] = run;
}

__global__ __launch_bounds__(256) void scatter_kernel(
    const int* __restrict__ E2d_idx, const int* __restrict__ Edist_idx,
    int* __restrict__ cursor, int* __restrict__ order) {
    int g = blockIdx.x * 256 + threadIdx.x;
    if (g < NEFF) {
        int r = edge_row(g, E2d_idx, Edist_idx);
        int pos = atomicAdd(&cursor[r], 1);
        order[pos] = g;
    }
}

// ---------------- meta: per-sorted-edge precompute ----------------
__global__ __launch_bounds__(256) void meta_kernel(
    const int* __restrict__ order, const int* __restrict__ E2d_idx,
    const int* __restrict__ Edist_idx, const float* __restrict__ Edist_val,
    const float* __restrict__ Z, const float* __restrict__ Z3d,
    int4* __restrict__ metaI, float4* __restrict__ metaF,
    float4* __restrict__ metaU) {
    int g = blockIdx.x * 256 + threadIdx.x;
    if (g >= NPAD) return;
    int eid = (g < NEFF) ? order[g] : -1;
    int row, col, ty, e2 = 0; float dval = 0.f;
    if (eid < 0)             { ty = 1; row = -1; col = 0; }
    else if (eid < E1N)      { ty = 0; row = E2d_idx[eid]; col = E2d_idx[E1N + eid]; e2 = eid; }
    else if (eid < E1N + NN) { ty = 1; int jj = eid - E1N; row = jj; col = jj + NN; }
    else { ty = 2; int g2 = eid - E1N - NN;
           row = Edist_idx[g2]; col = Edist_idx[E2N + g2]; dval = Edist_val[g2]; }
    int rs = (row < 0) ? 0 : row;
    float prx = Z[rs * 3], pry = Z[rs * 3 + 1], prz = Z[rs * 3 + 2];
    float pcx, pcy, pcz;
    if (col < NN) { pcx = Z[col * 3]; pcy = Z[col * 3 + 1]; pcz = Z[col * 3 + 2]; }
    else { int c = col - NN; pcx = Z3d[c * 3]; pcy = Z3d[c * 3 + 1]; pcz = Z3d[c * 3 + 2]; }
    float dx = prx - pcx, dy = pry - pcy, dz = prz - pcz;
    float dist = sqrtf(dx * dx + dy * dy + dz * dz + 1e-8f);
    float inv = 1.0f / dist;
    int vcol = (col < NN) ? col : -1;
    metaI[g] = make_int4(col, row, ty, e2);
    metaF[g] = make_float4(dist, dval, env_of(dist), env_of(dval));
    metaU[g] = (row >= 0)
        ? make_float4(dx * inv, dy * inv, dz * inv, __int_as_float(vcol))
        : make_float4(0.f, 0.f, 0.f, __int_as_float(-1));
}

// ---------------- prep: folded/bf16 weights (+ Wib for nodes MFMA) ----------------
__global__ __launch_bounds__(256) void prep_kernel(
    const float* __restrict__ W_phi1, const float* __restrict__ b_phi1,
    const float* __restrict__ W_e2d, const float* __restrict__ W_rbf,
    const float* __restrict__ W_phi2, const float* __restrict__ W_msg,
    const float* __restrict__ et, const float* __restrict__ W_i,
    ushort* __restrict__ W1c, ushort* __restrict__ W2b,
    ushort* __restrict__ Wmb, float* __restrict__ b_type,
    ushort* __restrict__ Wib) {
    int g = blockIdx.x * 256 + threadIdx.x;
    if (g < 32768) {
        int n = g >> 8, k = g & 255;
        float v;
        if (k < 128) v = W_phi1[n * 288 + k];
        else {
            int kk = k - 128;
            const float* Wsel = (kk < 64) ? W_e2d : W_rbf;  // both (128,64)
            int j = kk & 63;
            float s = 0.f;
            for (int a = 0; a < 128; ++a) s += W_phi1[n * 288 + 128 + a] * Wsel[a * 64 + j];
            v = s;
        }
        W1c[n * 256 + k] = f2bf(v);
    } else if (g < 81920) {
        int q = g - 32768; W2b[q] = f2bf(W_phi2[q]);
    } else if (g < 106496) {
        int q = g - 81920; Wmb[q] = f2bf(W_msg[q]);
    } else if (g < 106880) {
        int q = g - 106496; int ty = q >> 7, n = q & 127;
        float s = b_phi1[n];
        for (int a = 0; a < 32; ++a) s += W_phi1[n * 288 + 256 + a] * et[ty * 32 + a];
        b_type[q] = s;
    } else if (g < 139648) {
        int q = g - 106880; Wib[q] = f2bf(W_i[q]);
    }
}

// ---------------- featT: transpose E2d_feat (64,E1N) -> bf16 (E1N,64) ----------------
__global__ __launch_bounds__(256) void featT_kernel(
    const float* __restrict__ feat, ushort* __restrict__ featTb) {
    __shared__ float tile[64][65];
    const int t = threadIdx.x;
    const int cbase = blockIdx.x * 64;
    for (int i = t; i < 64 * 64; i += 256) {
        int k = i >> 6, e = i & 63;
        tile[k][e] = (cbase + e < E1N) ? feat[(size_t)k * E1N + cbase + e] : 0.f;
    }
    __syncthreads();
    for (int i = t; i < 64 * 64; i += 256) {
        int e = i >> 6, k = i & 63;
        if (cbase + e < E1N) featTb[(size_t)(cbase + e) * 64 + k] = f2bf(tile[k][e]);
    }
}

// ---------------- nodes (MFMA) ----------------
__global__ __launch_bounds__(256, 2) void nodes_mfma_kernel(
    const float* __restrict__ H, const float* __restrict__ H2d,
    const float* __restrict__ virt, const ushort* __restrict__ Wib,
    ushort* __restrict__ nodesb) {
    __shared__ ushort A[64][264];
    __shared__ ushort WB[128][132];

    const int t = threadIdx.x;
    const int gbase = blockIdx.x * 64;

    for (int i = t; i < 64 * 64; i += 256) {
        int e = i >> 6, q = i & 63;
        int row = gbase + e;
        float4 v;
        if (q < 32)          v = ld4(H + (size_t)((row < NN) ? row : row - NN) * 128 + q * 4);
        else if (row < NN)   v = ld4(H2d + (size_t)row * 128 + (q - 32) * 4);
        else                 v = ld4(virt + (q - 32) * 4);
        ushort tmp[4] = {f2bf(v.x), f2bf(v.y), f2bf(v.z), f2bf(v.w)};
        *reinterpret_cast<uint2*>(&A[e][q * 4]) = *reinterpret_cast<const uint2*>(tmp);
    }
    for (int i = t; i < 128 * 16; i += 256) {
        int n = i >> 4, q = i & 15;
        *reinterpret_cast<uint4*>(&WB[n][q * 8]) =
            *reinterpret_cast<const uint4*>(Wib + (size_t)n * 256 + q * 8);
    }
    __syncthreads();

    const int w  = t >> 6, lane = t & 63;
    const int mh = w >> 1, nh = w & 1;
    const int lr = lane >> 4, lc = lane & 15;
    const int ar0 = mh * 32 + lc;

    f32x4 acc[2][4];
#pragma unroll
    for (int mt = 0; mt < 2; ++mt)
#pragma unroll
        for (int nt = 0; nt < 4; ++nt) acc[mt][nt] = (f32x4){0.f, 0.f, 0.f, 0.f};
#pragma unroll
    for (int ks = 0; ks < 4; ++ks) {
        bf16x8 a0 = *reinterpret_cast<const bf16x8*>(&A[ar0][ks * 32 + lr * 8]);
        bf16x8 a1 = *reinterpret_cast<const bf16x8*>(&A[ar0 + 16][ks * 32 + lr * 8]);
#pragma unroll
        for (int nt = 0; nt < 4; ++nt) {
            int n = nh * 64 + nt * 16 + lc;
            bf16x8 b = *reinterpret_cast<const bf16x8*>(&WB[n][ks * 32 + lr * 8]);
            acc[0][nt] = __builtin_amdgcn_mfma_f32_16x16x32_bf16(a0, b, acc[0][nt], 0, 0, 0);
            acc[1][nt] = __builtin_amdgcn_mfma_f32_16x16x32_bf16(a1, b, acc[1][nt], 0, 0, 0);
        }
    }
    __syncthreads();
    for (int i = t; i < 128 * 16; i += 256) {
        int n = i >> 4, q = i & 15;
        *reinterpret_cast<uint4*>(&WB[n][q * 8]) =
            *reinterpret_cast<const uint4*>(Wib + (size_t)n * 256 + 128 + q * 8);
    }
    __syncthreads();
#pragma unroll
    for (int ks = 4; ks < 8; ++ks) {
        bf16x8 a0 = *reinterpret_cast<const bf16x8*>(&A[ar0][ks * 32 + lr * 8]);
        bf16x8 a1 = *reinterpret_cast<const bf16x8*>(&A[ar0 + 16][ks * 32 + lr * 8]);
#pragma unroll
        for (int nt = 0; nt < 4; ++nt) {
            int n = nh * 64 + nt * 16 + lc;
            bf16x8 b = *reinterpret_cast<const bf16x8*>(&WB[n][(ks - 4) * 32 + lr * 8]);
            acc[0][nt] = __builtin_amdgcn_mfma_f32_16x16x32_bf16(a0, b, acc[0][nt], 0, 0, 0);
            acc[1][nt] = __builtin_amdgcn_mfma_f32_16x16x32_bf16(a1, b, acc[1][nt], 0, 0, 0);
        }
    }
#pragma unroll
    for (int mt = 0; mt < 2; ++mt)
#pragma unroll
        for (int nt = 0; nt < 4; ++nt)
#pragma unroll
            for (int r = 0; r < 4; ++r) {
                int e  = mh * 32 + mt * 16 + lr * 4 + r;
                int ch = nh * 64 + nt * 16 + lc;
                nodesb[(size_t)(gbase + e) * 128 + ch] = f2bf(acc[mt][nt][r]);
            }
}

// ---------------- edge1: round-9 proven LDS-staged MFMA pipeline ----------------
__global__ __launch_bounds__(256, 2) void edge1_kernel(
    const ushort* __restrict__ nodesb, const ushort* __restrict__ featTb,
    const ushort* __restrict__ W1c, const ushort* __restrict__ W2b,
    const ushort* __restrict__ Wmb, const float* __restrict__ b_type,
    const float* __restrict__ b_phi2, const float* __restrict__ b_msg,
    const int4* __restrict__ metaI, const float4* __restrict__ metaF,
    ushort* __restrict__ payloadM) {

    // flat LDS: A1 staging stride 264; aliased later as hid (stride 136) at [0,8704)
    // + m_lds (stride 132) at [8704, 17152)
    __shared__ ushort A1f[TILE * 264 + 256];
    __shared__ ushort WB[128][132];
    __shared__ float  s_bt[3][128];
    __shared__ int    s_col[TILE], s_ty[TILE], s_e2[TILE];
    __shared__ float  s_dval[TILE], s_env2[TILE];

    ushort* hidp  = A1f;          // stride 136
    ushort* m_lds = A1f + 8704;   // stride 132 (conflict-free scalar stores)

    const int t = threadIdx.x;
    const int gbase = blockIdx.x * TILE;

    if (t < TILE) {
        int4 mi = metaI[gbase + t];
        s_col[t] = mi.x; s_ty[t] = mi.z; s_e2[t] = mi.w;
        float4 mf = metaF[gbase + t];
        s_dval[t] = mf.y; s_env2[t] = mf.w;
    }
    for (int i = t; i < 384; i += 256) ((float*)s_bt)[i] = b_type[i];
    __syncthreads();

    // ---- stage A1 = [nodes_bf16[col] | featT | rbf(dval)] and WB <- W1c K-half 0 ----
    for (int i = t; i < TILE * 16; i += 256) {     // left 128: 16B vector gather
        int e = i >> 4, q = i & 15;
        *reinterpret_cast<uint4*>(&A1f[e * 264 + q * 8]) =
            *reinterpret_cast<const uint4*>(nodesb + (size_t)s_col[e] * 128 + q * 8);
    }
    for (int i = t; i < TILE * 128; i += 256) {    // right 128
        int e = i >> 7, k = i & 127;
        int ty = s_ty[e];
        ushort v = 0;
        if (ty == 0) { if (k < 64) v = featTb[(size_t)s_e2[e] * 64 + k]; }
        else if (ty == 2) {
            if (k >= 64) {
                float dd = s_dval[e] - (float)(k - 64) * RBF_STEP;
                v = f2bf(__expf(-dd * dd * RBF_INV2W2) * s_env2[e]);
            }
        }
        A1f[e * 264 + 128 + k] = v;
    }
    for (int i = t; i < 128 * 16; i += 256) {      // WB <- W1c[:, 0:128]
        int n = i >> 4, q = i & 15;
        *reinterpret_cast<uint4*>(&WB[n][q * 8]) =
            *reinterpret_cast<const uint4*>(W1c + (size_t)n * 256 + q * 8);
    }
    __syncthreads();

    const int w  = t >> 6, lane = t & 63;
    const int mh = w >> 1, nh = w & 1;             // wave: 32 edges x 64 channels
    const int lr = lane >> 4, lc = lane & 15;
    const int ar0 = mh * 32 + lc;

    // ---- wd A-fragments in-register: rbf(dist) for edges ar0, ar0+16 ----
    const float4 mfA = metaF[gbase + ar0];
    const float4 mfB = metaF[gbase + ar0 + 16];
    bf16x8 ra0[2], ra1[2];
#pragma unroll
    for (int ks = 0; ks < 2; ++ks)
#pragma unroll
        for (int j = 0; j < 8; ++j) {
            float cc = (float)(ks * 32 + lr * 8 + j) * RBF_STEP;
            float tA = mfA.x - cc, tB = mfB.x - cc;
            ra0[ks][j] = (short)f2bf(__expf(-tA * tA * RBF_INV2W2) * mfA.z);
            ra1[ks][j] = (short)f2bf(__expf(-tB * tB * RBF_INV2W2) * mfB.z);
        }

    // ---- phi1: (64 x 256) @ W1c^T (B staged in LDS, 2 K-halves) ----
    f32x4 acc[2][4];
#pragma unroll
    for (int mt = 0; mt < 2; ++mt)
#pragma unroll
        for (int nt = 0; nt < 4; ++nt) acc[mt][nt] = (f32x4){0.f, 0.f, 0.f, 0.f};
#pragma unroll
    for (int ks = 0; ks < 4; ++ks) {
        bf16x8 a0 = *reinterpret_cast<const bf16x8*>(&A1f[ar0 * 264 + ks * 32 + lr * 8]);
        bf16x8 a1 = *reinterpret_cast<const bf16x8*>(&A1f[(ar0 + 16) * 264 + ks * 32 + lr * 8]);
#pragma unroll
        for (int nt = 0; nt < 4; ++nt) {
            int n = nh * 64 + nt * 16 + lc;
            bf16x8 b = *reinterpret_cast<const bf16x8*>(&WB[n][ks * 32 + lr * 8]);
            acc[0][nt] = __builtin_amdgcn_mfma_f32_16x16x32_bf16(a0, b, acc[0][nt], 0, 0, 0);
            acc[1][nt] = __builtin_amdgcn_mfma_f32_16x16x32_bf16(a1, b, acc[1][nt], 0, 0, 0);
        }
    }
    __syncthreads();
    for (int i = t; i < 128 * 16; i += 256) {      // WB <- W1c[:, 128:256]
        int n = i >> 4, q = i & 15;
        *reinterpret_cast<uint4*>(&WB[n][q * 8]) =
            *reinterpret_cast<const uint4*>(W1c + (size_t)n * 256 + 128 + q * 8);
    }
    __syncthreads();
#pragma unroll
    for (int ks = 4; ks < 8; ++ks) {
        bf16x8 a0 = *reinterpret_cast<const bf16x8*>(&A1f[ar0 * 264 + ks * 32 + lr * 8]);
        bf16x8 a1 = *reinterpret_cast<const bf16x8*>(&A1f[(ar0 + 16) * 264 + ks * 32 + lr * 8]);
#pragma unroll
        for (int nt = 0; nt < 4; ++nt) {
            int n = nh * 64 + nt * 16 + lc;
            bf16x8 b = *reinterpret_cast<const bf16x8*>(&WB[n][(ks - 4) * 32 + lr * 8]);
            acc[0][nt] = __builtin_amdgcn_mfma_f32_16x16x32_bf16(a0, b, acc[0][nt], 0, 0, 0);
            acc[1][nt] = __builtin_amdgcn_mfma_f32_16x16x32_bf16(a1, b, acc[1][nt], 0, 0, 0);
        }
    }
    __syncthreads();   // all A1 + WB reads complete

    // ---- silu -> hid; stage WB <- W2b c=0 ----
#pragma unroll
    for (int mt = 0; mt < 2; ++mt)
#pragma unroll
        for (int nt = 0; nt < 4; ++nt)
#pragma unroll
            for (int r = 0; r < 4; ++r) {
                int e  = mh * 32 + mt * 16 + lr * 4 + r;
                int ch = nh * 64 + nt * 16 + lc;
                float x = acc[mt][nt][r] + s_bt[s_ty[e]][ch];
                hidp[e * 136 + ch] = f2bf(x / (1.0f + __expf(-x)));
            }
    for (int i = t; i < 128 * 16; i += 256) {
        int n = i >> 4, q = i & 15;
        *reinterpret_cast<uint4*>(&WB[n][q * 8]) =
            *reinterpret_cast<const uint4*>(W2b + (size_t)n * 128 + q * 8);
    }
    __syncthreads();

    // ---- hoist hid A-fragments (shared across the 3 c-chunks) ----
    bf16x8 ha0[4], ha1[4];
#pragma unroll
    for (int ks = 0; ks < 4; ++ks) {
        ha0[ks] = *reinterpret_cast<const bf16x8*>(&hidp[ar0 * 136 + ks * 32 + lr * 8]);
        ha1[ks] = *reinterpret_cast<const bf16x8*>(&hidp[(ar0 + 16) * 136 + ks * 32 + lr * 8]);
    }

    // ---- phi2 + wd in 3 channel-chunks; m = phi*wd -> m_lds -> payload ----
#pragma unroll
    for (int c = 0; c < 3; ++c) {
        f32x4 p[2][4], g[2][4];
#pragma unroll
        for (int mt = 0; mt < 2; ++mt)
#pragma unroll
            for (int nt = 0; nt < 4; ++nt) {
                p[mt][nt] = (f32x4){0.f, 0.f, 0.f, 0.f};
                g[mt][nt] = (f32x4){0.f, 0.f, 0.f, 0.f};
            }
#pragma unroll
        for (int ks = 0; ks < 4; ++ks) {
#pragma unroll
            for (int nt = 0; nt < 4; ++nt) {
                int n = nh * 64 + nt * 16 + lc;
                bf16x8 b = *reinterpret_cast<const bf16x8*>(&WB[n][ks * 32 + lr * 8]);
                p[0][nt] = __builtin_amdgcn_mfma_f32_16x16x32_bf16(ha0[ks], b, p[0][nt], 0, 0, 0);
                p[1][nt] = __builtin_amdgcn_mfma_f32_16x16x32_bf16(ha1[ks], b, p[1][nt], 0, 0, 0);
            }
        }
#pragma unroll
        for (int ks = 0; ks < 2; ++ks) {
#pragma unroll
            for (int nt = 0; nt < 4; ++nt) {
                int n = c * 128 + nh * 64 + nt * 16 + lc;
                bf16x8 b = *reinterpret_cast<const bf16x8*>(Wmb + (size_t)n * 64 + ks * 32 + lr * 8);
                g[0][nt] = __builtin_amdgcn_mfma_f32_16x16x32_bf16(ra0[ks], b, g[0][nt], 0, 0, 0);
                g[1][nt] = __builtin_amdgcn_mfma_f32_16x16x32_bf16(ra1[ks], b, g[1][nt], 0, 0, 0);
            }
        }
        __syncthreads();               // WB reads for this c done; prev copy done
#pragma unroll
        for (int mt = 0; mt < 2; ++mt)
#pragma unroll
            for (int nt = 0; nt < 4; ++nt) {
                int d  = nh * 64 + nt * 16 + lc;
                float b2 = b_phi2[c * 128 + d];
                float bm = b_msg[c * 128 + d];
#pragma unroll
                for (int r = 0; r < 4; ++r) {
                    int e = mh * 32 + mt * 16 + lr * 4 + r;
                    m_lds[e * 132 + d] = f2bf((p[mt][nt][r] + b2) * (g[mt][nt][r] + bm));
                }
            }
        if (c < 2) {                   // stage next c's W2b slice
            for (int i = t; i < 128 * 16; i += 256) {
                int n = i >> 4, q = i & 15;
                *reinterpret_cast<uint4*>(&WB[n][q * 8]) =
                    *reinterpret_cast<const uint4*>(W2b + (size_t)((c + 1) * 128 + n) * 128 + q * 8);
            }
        }
        __syncthreads();               // m_lds complete + WB staged
        // coalesced copy m_lds[64][132] -> payloadM (8B units)
        for (int i = t; i < 2048; i += 256) {
            int e = i >> 5, q = i & 31;
            *reinterpret_cast<uint2*>(payloadM + (size_t)(gbase + e) * 384 + c * 128 + q * 4) =
                *reinterpret_cast<const uint2*>(m_lds + e * 132 + q * 4);
        }
    }
}

// ---------------- fallback: monolithic atomic edge kernel ----------------
__global__ __launch_bounds__(256, 2) void edge0_kernel(
    const ushort* __restrict__ nodesb, const float* __restrict__ V,
    const float* __restrict__ Z, const float* __restrict__ Z3d,
    const int* __restrict__ E2d_idx, const float* __restrict__ E2d_feat,
    const int* __restrict__ Edist_idx, const float* __restrict__ Edist_val,
    const ushort* __restrict__ W1c, const ushort* __restrict__ W2b,
    const ushort* __restrict__ Wmb, const float* __restrict__ b_type,
    const float* __restrict__ b_phi2, const float* __restrict__ b_msg,
    float* __restrict__ Hout, float* __restrict__ Vout) {

    __shared__ ushort A1[TILE][264];
    __shared__ float  s_bt[3][128];
    __shared__ int    s_row[TILE], s_col[TILE], s_ty[TILE], s_e2[TILE], s_vcol[TILE];
    __shared__ float  s_dist[TILE], s_dval[TILE], s_env[TILE], s_env2[TILE];
    __shared__ float  s_unit[TILE][3];
    ushort (*hid)[136] = reinterpret_cast<ushort(*)[136]>(&A1[0][0]);

    const int t = threadIdx.x;
    const int gbase = blockIdx.x * TILE;
    if (t < TILE) {
        int gpos = gbase + t;
        int eid = (gpos < NEFF) ? gpos : -1;
        int row, col, ty, e2 = 0; float dval = 0.f;
        if (eid < 0)             { ty = 1; row = -1; col = 0; }
        else if (eid < E1N)      { ty = 0; row = E2d_idx[eid]; col = E2d_idx[E1N + eid]; e2 = eid; }
        else if (eid < E1N + NN) { ty = 1; int jj = eid - E1N; row = jj; col = jj + NN; }
        else { ty = 2; int g2 = eid - E1N - NN;
               row = Edist_idx[g2]; col = Edist_idx[E2N + g2]; dval = Edist_val[g2]; }
        int rs = (row < 0) ? 0 : row;
        float prx = Z[rs * 3], pry = Z[rs * 3 + 1], prz = Z[rs * 3 + 2];
        float pcx, pcy, pcz;
        if (col < NN) { pcx = Z[col * 3]; pcy = Z[col * 3 + 1]; pcz = Z[col * 3 + 2]; }
        else { int c = col - NN; pcx = Z3d[c * 3]; pcy = Z3d[c * 3 + 1]; pcz = Z3d[c * 3 + 2]; }
        float dx = prx - pcx, dy = pry - pcy, dz = prz - pcz;
        float dist = sqrtf(dx * dx + dy * dy + dz * dz + 1e-8f);
        float inv = 1.0f / dist;
        s_row[t] = row; s_col[t] = col; s_ty[t] = ty; s_e2[t] = e2;
        s_vcol[t] = (col < NN) ? col : -1;
        s_unit[t][0] = dx * inv; s_unit[t][1] = dy * inv; s_unit[t][2] = dz * inv;
        s_dist[t] = dist; s_dval[t] = dval;
        s_env[t] = env_of(dist); s_env2[t] = env_of(dval);
    }
    for (int i = t; i < 384; i += 256) ((float*)s_bt)[i] = b_type[i];
    __syncthreads();

    for (int i = t; i < TILE * 16; i += 256) {
        int e = i >> 4, q = i & 15;
        *reinterpret_cast<uint4*>(&A1[e][q * 8]) =
            *reinterpret_cast<const uint4*>(nodesb + (size_t)s_col[e] * 128 + q * 8);
    }
    for (int i = t; i < TILE * 128; i += 256) {
        int k = i >> 6, e = i & 63;
        int ty = s_ty[e];
        float v = 0.f;
        if (ty == 0) { if (k < 64) v = E2d_feat[(size_t)k * E1N + s_e2[e]]; }
        else if (ty == 2) {
            if (k >= 64) {
                float dd = s_dval[e] - (float)(k - 64) * RBF_STEP;
                v = __expf(-dd * dd * RBF_INV2W2) * s_env2[e];
            }
        }
        A1[e][128 + k] = f2bf(v);
    }
    __syncthreads();

    const int w  = t >> 6, lane = t & 63;
    const int mh = w >> 1, nh = w & 1;
    const int lr = lane >> 4, lc = lane & 15;
    const int ar0 = mh * 32 + lc;

    bf16x8 ra0[2], ra1[2];
    {
        float dA = s_dist[ar0],      eA = s_env[ar0];
        float dB = s_dist[ar0 + 16], eB = s_env[ar0 + 16];
#pragma unroll
        for (int ks = 0; ks < 2; ++ks)
#pragma unroll
            for (int j = 0; j < 8; ++j) {
                float c  = (float)(ks * 32 + lr * 8 + j) * RBF_STEP;
                float tA = dA - c, tB = dB - c;
                ra0[ks][j] = (short)f2bf(__expf(-tA * tA * RBF_INV2W2) * eA);
                ra1[ks][j] = (short)f2bf(__expf(-tB * tB * RBF_INV2W2) * eB);
            }
    }

    f32x4 acc[2][4];
#pragma unroll
    for (int mt = 0; mt < 2; ++mt)
#pragma unroll
        for (int nt = 0; nt < 4; ++nt) acc[mt][nt] = (f32x4){0.f, 0.f, 0.f, 0.f};
#pragma unroll
    for (int ks = 0; ks < 8; ++ks) {
        bf16x8 a0 = *reinterpret_cast<const bf16x8*>(&A1[ar0][ks * 32 + lr * 8]);
        bf16x8 a1 = *reinterpret_cast<const bf16x8*>(&A1[ar0 + 16][ks * 32 + lr * 8]);
#pragma unroll
        for (int nt = 0; nt < 4; ++nt) {
            int n = nh * 64 + nt * 16 + lc;
            bf16x8 b = *reinterpret_cast<const bf16x8*>(W1c + (size_t)n * 256 + ks * 32 + lr * 8);
            acc[0][nt] = __builtin_amdgcn_mfma_f32_16x16x32_bf16(a0, b, acc[0][nt], 0, 0, 0);
            acc[1][nt] = __builtin_amdgcn_mfma_f32_16x16x32_bf16(a1, b, acc[1][nt], 0, 0, 0);
        }
    }
    __syncthreads();
#pragma unroll
    for (int mt = 0; mt < 2; ++mt)
#pragma unroll
        for (int nt = 0; nt < 4; ++nt)
#pragma unroll
            for (int r = 0; r < 4; ++r) {
                int e  = mh * 32 + mt * 16 + lr * 4 + r;
                int ch = nh * 64 + nt * 16 + lc;
                float x = acc[mt][nt][r] + s_bt[s_ty[e]][ch];
                hid[e][ch] = f2bf(x / (1.0f + __expf(-x)));
            }
    __syncthreads();

    f32x4 vgr[2][4];
#pragma unroll
    for (int c = 0; c < 3; ++c) {
        f32x4 p[2][4], g[2][4];
#pragma unroll
        for (int mt = 0; mt < 2; ++mt)
#pragma unroll
            for (int nt = 0; nt < 4; ++nt) {
                p[mt][nt] = (f32x4){0.f, 0.f, 0.f, 0.f};
                g[mt][nt] = (f32x4){0.f, 0.f, 0.f, 0.f};
            }
#pragma unroll
        for (int ks = 0; ks < 4; ++ks) {
            bf16x8 a0 = *reinterpret_cast<const bf16x8*>(&hid[ar0][ks * 32 + lr * 8]);
            bf16x8 a1 = *reinterpret_cast<const bf16x8*>(&hid[ar0 + 16][ks * 32 + lr * 8]);
#pragma unroll
            for (int nt = 0; nt < 4; ++nt) {
                int n = c * 128 + nh * 64 + nt * 16 + lc;
                bf16x8 b = *reinterpret_cast<const bf16x8*>(W2b + (size_t)n * 128 + ks * 32 + lr * 8);
                p[0][nt] = __builtin_amdgcn_mfma_f32_16x16x32_bf16(a0, b, p[0][nt], 0, 0, 0);
                p[1][nt] = __builtin_amdgcn_mfma_f32_16x16x32_bf16(a1, b, p[1][nt], 0, 0, 0);
            }
        }
#pragma unroll
        for (int ks = 0; ks < 2; ++ks) {
#pragma unroll
            for (int nt = 0; nt < 4; ++nt) {
                int n = c * 128 + nh * 64 + nt * 16 + lc;
                bf16x8 b = *reinterpret_cast<const bf16x8*>(Wmb + (size_t)n * 64 + ks * 32 + lr * 8);
                g[0][nt] = __builtin_amdgcn_mfma_f32_16x16x32_bf16(ra0[ks], b, g[0][nt], 0, 0, 0);
                g[1][nt] = __builtin_amdgcn_mfma_f32_16x16x32_bf16(ra1[ks], b, g[1][nt], 0, 0, 0);
            }
        }
#pragma unroll
        for (int mt = 0; mt < 2; ++mt)
#pragma unroll
            for (int nt = 0; nt < 4; ++nt) {
                int d  = nh * 64 + nt * 16 + lc;
                float b2 = b_phi2[c * 128 + d];
                float bm = b_msg[c * 128 + d];
#pragma unroll
                for (int r = 0; r < 4; ++r) {
                    int e = mh * 32 + mt * 16 + lr * 4 + r;
                    float m = (p[mt][nt][r] + b2) * (g[mt][nt][r] + bm);
                    int row = s_row[e];
                    if (c == 0) {
                        if (row >= 0) unsafeAtomicAdd(&Hout[(size_t)row * 128 + d], m);
                    } else if (c == 1) {
                        vgr[mt][nt][r] = m;
                    } else if (row >= 0) {
                        float vgv = vgr[mt][nt][r];
                        int vc = s_vcol[e];
                        float vx = 0.f, vy = 0.f, vz = 0.f;
                        if (vc >= 0) {
                            const float* vp = V + ((size_t)vc * 128 + d) * 3;
                            vx = vp[0]; vy = vp[1]; vz = vp[2];
                        }
                        float* vo = Vout + ((size_t)row * 128 + d) * 3;
                        unsafeAtomicAdd(vo + 0, vx * vgv + s_unit[e][0] * m);
                        unsafeAtomicAdd(vo + 1, vy * vgv + s_unit[e][1] * m);
                        unsafeAtomicAdd(vo + 2, vz * vgv + s_unit[e][2] * m);
                    }
                }
            }
    }
}

// ---------------- reduce: all rows, pure write, 4-deep MLP both sides ----------------
__global__ __launch_bounds__(256) void reduce_kernel(
    const ushort* __restrict__ payloadM, const float4* __restrict__ metaU,
    const float* __restrict__ V, const int* __restrict__ start,
    float* __restrict__ Hout, float* __restrict__ Vout) {
    const int t = threadIdx.x;
    const int rbase = blockIdx.x * 4;
    const bool hside = (t < 128);
    const int d = hside ? t : (t - 128);
    for (int nr = 0; nr < 4; ++nr) {
        int r = rbase + nr;
        if (r >= NN) return;
        int a = start[r], b = start[r + 1];
        int n = b - a;
        if (hside) {
            const ushort* base = payloadM + (size_t)a * 384 + d;
            float a0 = 0.f, a1 = 0.f, a2 = 0.f, a3 = 0.f;
            int i = 0;
            for (; i + 4 <= n; i += 4) {
                a0 += bf2f(base[(size_t)i * 384]);
                a1 += bf2f(base[(size_t)(i + 1) * 384]);
                a2 += bf2f(base[(size_t)(i + 2) * 384]);
                a3 += bf2f(base[(size_t)(i + 3) * 384]);
            }
            for (; i < n; ++i) a0 += bf2f(base[(size_t)i * 384]);
            Hout[(size_t)r * 128 + d] = clip100((a0 + a1) + (a2 + a3));
        } else {
            const ushort* base = payloadM + (size_t)a * 384;
            const float4* ub = metaU + a;
            float ax = 0.f, ay = 0.f, az = 0.f;
            float bx = 0.f, by = 0.f, bz = 0.f;
            int i = 0;
            for (; i + 4 <= n; i += 4) {
                const ushort* pm0 = base + (size_t)i * 384;
                const ushort* pm1 = base + (size_t)(i + 1) * 384;
                const ushort* pm2 = base + (size_t)(i + 2) * 384;
                const ushort* pm3 = base + (size_t)(i + 3) * 384;
                float vg0 = bf2f(pm0[128 + d]), rg0 = bf2f(pm0[256 + d]);
                float vg1 = bf2f(pm1[128 + d]), rg1 = bf2f(pm1[256 + d]);
                float vg2 = bf2f(pm2[128 + d]), rg2 = bf2f(pm2[256 + d]);
                float vg3 = bf2f(pm3[128 + d]), rg3 = bf2f(pm3[256 + d]);
                float4 u0 = ub[i], u1 = ub[i + 1], u2 = ub[i + 2], u3 = ub[i + 3];
                int vc0 = __float_as_int(u0.w);
                int vc1 = __float_as_int(u1.w);
                int vc2 = __float_as_int(u2.w);
                int vc3 = __float_as_int(u3.w);
                if (vc0 >= 0) {
                    const float* vp = V + (size_t)vc0 * 384 + d * 3;
                    ax += vg0 * vp[0]; ay += vg0 * vp[1]; az += vg0 * vp[2];
                }
                if (vc1 >= 0) {
                    const float* vp = V + (size_t)vc1 * 384 + d * 3;
                    bx += vg1 * vp[0]; by += vg1 * vp[1]; bz += vg1 * vp[2];
                }
                if (vc2 >= 0) {
                    const float* vp = V + (size_t)vc2 * 384 + d * 3;
                    ax += vg2 * vp[0]; ay += vg2 * vp[1]; az += vg2 * vp[2];
                }
                if (vc3 >= 0) {
                    const float* vp = V + (size_t)vc3 * 384 + d * 3;
                    bx += vg3 * vp[0]; by += vg3 * vp[1]; bz += vg3 * vp[2];
                }
                ax += rg0 * u0.x; ay += rg0 * u0.y; az += rg0 * u0.z;
                bx += rg1 * u1.x; by += rg1 * u1.y; bz += rg1 * u1.z;
                ax += rg2 * u2.x; ay += rg2 * u2.y; az += rg2 * u2.z;
                bx += rg3 * u3.x; by += rg3 * u3.y; bz += rg3 * u3.z;
            }
            for (; i < n; ++i) {
                const ushort* pm0 = base + (size_t)i * 384;
                float vg0 = bf2f(pm0[128 + d]), rg0 = bf2f(pm0[256 + d]);
                float4 u0 = ub[i];
                int vc0 = __float_as_int(u0.w);
                if (vc0 >= 0) {
                    const float* vp = V + (size_t)vc0 * 384 + d * 3;
                    ax += vg0 * vp[0]; ay += vg0 * vp[1]; az += vg0 * vp[2];
                }
                ax += rg0 * u0.x; ay += rg0 * u0.y; az += rg0 * u0.z;
            }
            float* vo = Vout + (size_t)r * 384 + d * 3;
            vo[0] = clip100(ax + bx);
            vo[1] = clip100(ay + by);
            vo[2] = clip100(az + bz);
        }
    }
}

extern "C" void kernel_launch(void* const* d_in, const int* in_sizes, int n_in,
                              void* d_out, int out_size, void* d_ws, size_t ws_size,
                              hipStream_t stream) {
    const float* H         = (const float*)d_in[0];
    const float* V         = (const float*)d_in[1];
    const float* Z         = (const float*)d_in[2];
    const float* H2d       = (const float*)d_in[4];
    const int*   E2d_idx   = (const int*)d_in[6];
    const float* E2d_feat  = (const float*)d_in[7];
    const float* Z3d       = (const float*)d_in[8];
    const int*   Edist_idx = (const int*)d_in[10];
    const float* Edist_val = (const float*)d_in[11];
    const float* virt      = (const float*)d_in[12];
    const float* et        = (const float*)d_in[13];
    const float* W_rbf     = (const float*)d_in[14];
    const float* W_e2d     = (const float*)d_in[15];
    const float* W_i       = (const float*)d_in[16];
    const float* W_phi1    = (const float*)d_in[17];
    const float* b_phi1    = (const float*)d_in[18];
    const float* W_phi2    = (const float*)d_in[19];
    const float* b_phi2    = (const float*)d_in[20];
    const float* W_msg     = (const float*)d_in[21];
    const float* b_msg     = (const float*)d_in[22];

    ushort* nodesb  = (ushort*)d_ws;                 // 40000*128 bf16
    ushort* W1c     = nodesb + 5120000;              // (128,256)
    ushort* W2b     = W1c + 32768;                   // (384,128)
    ushort* Wmb     = W2b + 49152;                   // (384,64)
    ushort* Wib     = Wmb + 24576;                   // (128,256)
    float*  b_type  = (float*)(Wib + 32768);         // (3,128)
    ushort* featTb  = (ushort*)(b_type + 384);       // (E1N,64) bf16
    int*    hist    = (int*)(featTb + (size_t)E1N * 64);
    int*    cursor  = hist + NN;
    int*    start   = cursor + NN;                   // NN+1
    int*    order   = start + NN + 1;                // NPAD
    int4*   metaI   = (int4*)(((size_t)(order + NPAD) + 15) & ~(size_t)15);
    float4* metaF   = (float4*)(metaI + NPAD);
    float4* metaU   = metaF + NPAD;

    size_t fixed = (size_t)((char*)(metaU + NPAD) - (char*)d_ws);
    size_t poff  = (fixed + 255) & ~(size_t)255;
    size_t need  = poff + (size_t)NPAD * 384 * sizeof(ushort);   // full bf16 payload
    const bool big = (ws_size >= need);
    ushort* payloadM = (ushort*)((char*)d_ws + poff);

    float* Hout = (float*)d_out;
    float* Vout = Hout + (size_t)NN * 128;

    prep_kernel<<<(139648 + 255) / 256, 256, 0, stream>>>(
        W_phi1, b_phi1, W_e2d, W_rbf, W_phi2, W_msg, et, W_i,
        W1c, W2b, Wmb, b_type, Wib);
    nodes_mfma_kernel<<<(2 * NN) / 64, 256, 0, stream>>>(H, H2d, virt, Wib, nodesb);

    if (big) {
        hipMemsetAsync(hist, 0, NN * sizeof(int), stream);
        featT_kernel<<<(E1N + 63) / 64, 256, 0, stream>>>(E2d_feat, featTb);
        hist_kernel<<<(NEFF + 255) / 256, 256, 0, stream>>>(E2d_idx, Edist_idx, hist);
        scan_kernel<<<1, 256, 0, stream>>>(hist, start, cursor);
        scatter_kernel<<<(NEFF + 255) / 256, 256, 0, stream>>>(E2d_idx, Edist_idx, cursor, order);
        meta_kernel<<<(NPAD + 255) / 256, 256, 0, stream>>>(
            order, E2d_idx, Edist_idx, Edist_val, Z, Z3d, metaI, metaF, metaU);
        edge1_kernel<<<NBLK, 256, 0, stream>>>(
            nodesb, featTb, W1c, W2b, Wmb, b_type, b_phi2, b_msg,
            metaI, metaF, payloadM);
        reduce_kernel<<<(NN + 3) / 4, 256, 0, stream>>>(
            payloadM, metaU, V, start, Hout, Vout);
    } else {
        hipMemsetAsync(d_out, 0, (size_t)out_size * sizeof(float), stream);
        edge0_kernel<<<NBLK, 256, 0, stream>>>(
            nodesb, V, Z, Z3d, E2d_idx, E2d_feat, Edist_idx, Edist_val,
            W1c, W2b, Wmb, b_type, b_phi2, b_msg, Hout, Vout);
    }
}